// Round 2
// baseline (959.944 us; speedup 1.0000x reference)
//
#include <hip/hip_runtime.h>
#include <hip/hip_bf16.h>
#include <math.h>

// Problem constants (fixed by the reference)
#define F_   30
#define E_   16
#define B_   4096
#define IN_  480      // F*E
#define H1_  1024
#define H2_  512
#define K_   32
#define HH_  512
#define D_   3
#define V_   10000
#define EPS_ 1e-5f

// ---------------------------------------------------------------------------
// emb[b, f*16+e] = tables[f, x[f,b], e]   (float4 per thread)
__global__ __launch_bounds__(256) void gather_kernel(const int* __restrict__ x,
                                                     const float* __restrict__ tables,
                                                     float* __restrict__ emb) {
    int idx = blockIdx.x * 256 + threadIdx.x;          // B_*F_*4 total
    int b  = idx / (F_ * 4);
    int r  = idx - b * (F_ * 4);
    int f  = r >> 2;
    int e4 = r & 3;
    int row = x[f * B_ + b];
    const float4* src = reinterpret_cast<const float4*>(tables + ((size_t)f * V_ + row) * E_) + e4;
    reinterpret_cast<float4*>(emb + (size_t)b * IN_ + f * E_)[e4] = *src;
}

// ---------------------------------------------------------------------------
// C[M,N] = A[M,K] @ W[K,N] + bias[N].  M=4096 fixed. 64x64 tile, 256 thr, 4x4/thr.
__global__ __launch_bounds__(256) void gemm64(const float* __restrict__ A,
                                              const float* __restrict__ W,
                                              const float* __restrict__ bias,
                                              float* __restrict__ C,
                                              int N, int K) {
    __shared__ float sA[16][68];   // [k][row], pad 68 keeps float4 alignment
    __shared__ float sB[16][68];   // [k][col]
    const int tid = threadIdx.x;
    const int tx = tid & 15, ty = tid >> 4;
    const int bm = blockIdx.x * 64;
    const int bn = blockIdx.y * 64;
    float acc[4][4] = {};
    for (int k0 = 0; k0 < K; k0 += 16) {
#pragma unroll
        for (int i = 0; i < 4; i++) {
            int li = tid + i * 256;
            int r = li >> 4, c = li & 15;
            sA[c][r] = A[(size_t)(bm + r) * K + (k0 + c)];
        }
#pragma unroll
        for (int i = 0; i < 4; i++) {
            int li = tid + i * 256;
            int r = li >> 6, c = li & 63;
            sB[r][c] = W[(size_t)(k0 + r) * N + (bn + c)];
        }
        __syncthreads();
#pragma unroll
        for (int k = 0; k < 16; k++) {
            float a0 = sA[k][ty * 4 + 0], a1 = sA[k][ty * 4 + 1];
            float a2 = sA[k][ty * 4 + 2], a3 = sA[k][ty * 4 + 3];
            float b0 = sB[k][tx * 4 + 0], b1 = sB[k][tx * 4 + 1];
            float b2 = sB[k][tx * 4 + 2], b3 = sB[k][tx * 4 + 3];
            acc[0][0] += a0 * b0; acc[0][1] += a0 * b1; acc[0][2] += a0 * b2; acc[0][3] += a0 * b3;
            acc[1][0] += a1 * b0; acc[1][1] += a1 * b1; acc[1][2] += a1 * b2; acc[1][3] += a1 * b3;
            acc[2][0] += a2 * b0; acc[2][1] += a2 * b1; acc[2][2] += a2 * b2; acc[2][3] += a2 * b3;
            acc[3][0] += a3 * b0; acc[3][1] += a3 * b1; acc[3][2] += a3 * b2; acc[3][3] += a3 * b3;
        }
        __syncthreads();
    }
#pragma unroll
    for (int i = 0; i < 4; i++) {
#pragma unroll
        for (int j = 0; j < 4; j++) {
            int col = bn + tx * 4 + j;
            C[(size_t)(bm + ty * 4 + i) * N + col] = acc[i][j] + bias[col];
        }
    }
}

// ---------------------------------------------------------------------------
// Partial column sums/sumsq with atomics. Grid: (N/64, 32 slabs of 128 rows).
__global__ __launch_bounds__(256) void colpartial(const float* __restrict__ Z, int N,
                                                  float* __restrict__ colsum,
                                                  float* __restrict__ colsumsq) {
    int lc = threadIdx.x & 63;
    int c  = blockIdx.x * 64 + lc;
    int rg = threadIdx.x >> 6;
    int r0 = blockIdx.y * 128 + rg;
    float s = 0.f, ss = 0.f;
#pragma unroll 8
    for (int k = 0; k < 32; k++) {
        float v = Z[(size_t)(r0 + 4 * k) * N + c];
        s += v; ss += v * v;
    }
    __shared__ float sh[2][4][64];
    sh[0][rg][lc] = s;
    sh[1][rg][lc] = ss;
    __syncthreads();
    if (threadIdx.x < 64) {
        int cc = blockIdx.x * 64 + threadIdx.x;
        float S  = sh[0][0][threadIdx.x] + sh[0][1][threadIdx.x] + sh[0][2][threadIdx.x] + sh[0][3][threadIdx.x];
        float SS = sh[1][0][threadIdx.x] + sh[1][1][threadIdx.x] + sh[1][2][threadIdx.x] + sh[1][3][threadIdx.x];
        atomicAdd(&colsum[cc], S);
        atomicAdd(&colsumsq[cc], SS);
    }
}

// ---------------------------------------------------------------------------
// In-place BN (biased var) + ReLU; stats finalized inline from sums.
__global__ __launch_bounds__(256) void bn_relu(float* __restrict__ Z, int N,
                                               const float* __restrict__ colsum,
                                               const float* __restrict__ colsumsq,
                                               const float* __restrict__ g,
                                               const float* __restrict__ bt) {
    int idx = blockIdx.x * 256 + threadIdx.x;          // over B_*N/4
    float4 v = reinterpret_cast<float4*>(Z)[idx];
    int c0 = (idx * 4) % N;
    float r[4] = {v.x, v.y, v.z, v.w};
#pragma unroll
    for (int q = 0; q < 4; q++) {
        int c = c0 + q;
        float S = colsum[c], SS = colsumsq[c];
        float m = S * (1.f / B_);
        float var = (SS - S * m) * (1.f / B_);
        float rs = rsqrtf(var + EPS_);
        r[q] = fmaxf(0.f, g[c] * (r[q] - m) * rs + bt[c]);
    }
    reinterpret_cast<float4*>(Z)[idx] = make_float4(r[0], r[1], r[2], r[3]);
}

// ---------------------------------------------------------------------------
// Adapter for one batch row per block:
// a = D1[b]@u0; c = a@hyper[b]; t = sigmoid(c@v0+bl0); a2 = t@u1; c2 = a2@hyper[b];
// T2[b] = c2@v1 + bl1
__global__ __launch_bounds__(256) void adapter_kernel(const float* __restrict__ D1,
                                                      const float* __restrict__ hyper,
                                                      const float* __restrict__ u0,
                                                      const float* __restrict__ v0,
                                                      const float* __restrict__ u1,
                                                      const float* __restrict__ v1,
                                                      const float* __restrict__ bl0,
                                                      const float* __restrict__ bl1,
                                                      float* __restrict__ T2) {
    int b = blockIdx.x, t = threadIdx.x;
    __shared__ float sD1[512];
    __shared__ float sH[1024];
    __shared__ float sa[32], sc[32], st[32], sa2[32], sc2[32];
    sD1[t]       = D1[(size_t)b * 512 + t];
    sD1[t + 256] = D1[(size_t)b * 512 + t + 256];
#pragma unroll
    for (int i = 0; i < 4; i++) sH[t + i * 256] = hyper[(size_t)b * 1024 + t + i * 256];
    __syncthreads();
    {   // a[i] = sum_f sD1[f] * u0[f,i] : 8 threads per output i
        int i = t >> 3, lf = t & 7;
        float p = 0.f;
        for (int f = lf; f < 512; f += 8) p += sD1[f] * u0[f * 32 + i];
        p += __shfl_down(p, 4, 8);
        p += __shfl_down(p, 2, 8);
        p += __shfl_down(p, 1, 8);
        if (lf == 0) sa[i] = p;
    }
    __syncthreads();
    if (t < 32) {
        float c = 0.f;
#pragma unroll
        for (int i = 0; i < 32; i++) c += sa[i] * sH[i * 32 + t];
        sc[t] = c;
    }
    __syncthreads();
    if (t < 32) {
        float t0 = bl0[t];
#pragma unroll
        for (int k = 0; k < 32; k++) t0 += sc[k] * v0[k * 32 + t];
        st[t] = 1.f / (1.f + expf(-t0));
    }
    __syncthreads();
    if (t < 32) {
        float a2 = 0.f;
#pragma unroll
        for (int f = 0; f < 32; f++) a2 += st[f] * u1[f * 32 + t];
        sa2[t] = a2;
    }
    __syncthreads();
    if (t < 32) {
        float c2 = 0.f;
#pragma unroll
        for (int i = 0; i < 32; i++) c2 += sa2[i] * sH[i * 32 + t];
        sc2[t] = c2;
    }
    __syncthreads();
#pragma unroll
    for (int q = 0; q < 2; q++) {
        int j = t + q * 256;
        float accv = bl1[j];
#pragma unroll
        for (int k = 0; k < 32; k++) accv += sc2[k] * v1[k * 512 + j];
        T2[(size_t)b * 512 + j] = accv;
    }
}

// ---------------------------------------------------------------------------
// Final per-domain head: BN(t2, unbiased) -> +D1 residual -> dot wo -> sigmoid
__global__ __launch_bounds__(256) void head_kernel(const float* __restrict__ T2,
                                                   const float* __restrict__ D1,
                                                   const float* __restrict__ colsum,
                                                   const float* __restrict__ colsumsq,
                                                   const float* __restrict__ g1,
                                                   const float* __restrict__ b1,
                                                   const float* __restrict__ wo,
                                                   const float* __restrict__ bo,
                                                   float* __restrict__ outs) {
    int b = blockIdx.x, t = threadIdx.x;
    float p = 0.f;
#pragma unroll
    for (int q = 0; q < 2; q++) {
        int j = t + q * 256;
        float S = colsum[j], SS = colsumsq[j];
        float m = S * (1.f / B_);
        float var = (SS - S * m) * (1.f / (B_ - 1));
        float rs = rsqrtf(var + EPS_);
        float di = g1[j] * (T2[(size_t)b * H2_ + j] - m) * rs + b1[j] + D1[(size_t)b * H2_ + j];
        p += di * wo[j];
    }
    p += __shfl_down(p, 32); p += __shfl_down(p, 16); p += __shfl_down(p, 8);
    p += __shfl_down(p, 4);  p += __shfl_down(p, 2);  p += __shfl_down(p, 1);
    __shared__ float sw[4];
    if ((t & 63) == 0) sw[t >> 6] = p;
    __syncthreads();
    if (t == 0) {
        float logit = sw[0] + sw[1] + sw[2] + sw[3] + bo[0];
        outs[b] = 1.f / (1.f + expf(-logit));
    }
}

__global__ __launch_bounds__(256) void zero_kernel(float* __restrict__ p, int n) {
    int i = blockIdx.x * 256 + threadIdx.x;
    if (i < n) p[i] = 0.f;
}

__global__ __launch_bounds__(256) void select_kernel(const int* __restrict__ x,
                                                     const float* __restrict__ outs,
                                                     float* __restrict__ out) {
    int b = blockIdx.x * 256 + threadIdx.x;
    if (b < B_) {
        int d = x[(F_ - 1) * B_ + b];
        out[b] = outs[(size_t)d * B_ + b];
    }
}

// ---------------------------------------------------------------------------
extern "C" void kernel_launch(void* const* d_in, const int* in_sizes, int n_in,
                              void* d_out, int out_size, void* d_ws, size_t ws_size,
                              hipStream_t stream) {
    const int*   x      = (const int*)  d_in[0];
    const float* tables = (const float*)d_in[1];
    const float* dW0  = (const float*)d_in[2];
    const float* db0  = (const float*)d_in[3];
    const float* dg0  = (const float*)d_in[4];
    const float* dbt0 = (const float*)d_in[5];
    const float* dW1  = (const float*)d_in[6];
    const float* db1  = (const float*)d_in[7];
    const float* dg1  = (const float*)d_in[8];
    const float* dbt1 = (const float*)d_in[9];
    const float* dWo  = (const float*)d_in[10];
    const float* dbo  = (const float*)d_in[11];
    const float* hW0  = (const float*)d_in[12];
    const float* hb0  = (const float*)d_in[13];
    const float* hg0  = (const float*)d_in[14];
    const float* hbt0 = (const float*)d_in[15];
    const float* hW1  = (const float*)d_in[16];
    const float* hb1  = (const float*)d_in[17];
    const float* hg1  = (const float*)d_in[18];
    const float* hbt1 = (const float*)d_in[19];
    const float* u0   = (const float*)d_in[20];
    const float* u1   = (const float*)d_in[21];
    const float* v0   = (const float*)d_in[22];
    const float* v1   = (const float*)d_in[23];
    const float* bl0  = (const float*)d_in[24];
    const float* bl1  = (const float*)d_in[25];
    const float* g1   = (const float*)d_in[26];
    const float* b1   = (const float*)d_in[27];
    float* out = (float*)d_out;

    float* ws   = (float*)d_ws;
    float* emb  = ws;                          // 4096*480
    float* Z0   = emb + (size_t)B_ * IN_;      // 4096*512
    float* Z1   = Z0  + (size_t)B_ * HH_;      // 4096*1024  (becomes hyper)
    float* ZD0  = Z1  + (size_t)B_ * H1_;      // 4096*1024
    float* D1   = ZD0 + (size_t)B_ * H1_;      // 4096*512
    float* T2   = D1  + (size_t)B_ * H2_;      // 4096*512
    float* outs = T2  + (size_t)B_ * H2_;      // 3*4096
    float* stats = outs + 3 * (size_t)B_;      // 11 stages * 2048 floats

    auto stg = [&](int s) { return stats + (size_t)s * 2048; };

    zero_kernel<<<(11 * 2048 + 255) / 256, 256, 0, stream>>>(stats, 11 * 2048);
    gather_kernel<<<B_ * F_ * 4 / 256, 256, 0, stream>>>(x, tables, emb);

    // hyper-net layer 0: [B,480]@[480,512]
    gemm64<<<dim3(64, 8), 256, 0, stream>>>(emb, hW0, hb0, Z0, HH_, IN_);
    colpartial<<<dim3(8, 32), 256, 0, stream>>>(Z0, HH_, stg(0), stg(0) + 1024);
    bn_relu<<<B_ * HH_ / 4 / 256, 256, 0, stream>>>(Z0, HH_, stg(0), stg(0) + 1024, hg0, hbt0);
    // hyper-net layer 1: [B,512]@[512,1024]
    gemm64<<<dim3(64, 16), 256, 0, stream>>>(Z0, hW1, hb1, Z1, H1_, HH_);
    colpartial<<<dim3(16, 32), 256, 0, stream>>>(Z1, H1_, stg(1), stg(1) + 1024);
    bn_relu<<<B_ * H1_ / 4 / 256, 256, 0, stream>>>(Z1, H1_, stg(1), stg(1) + 1024, hg1, hbt1);

    for (int d = 0; d < D_; d++) {
        int s = 2 + d * 3;
        gemm64<<<dim3(64, 16), 256, 0, stream>>>(emb, dW0 + (size_t)d * IN_ * H1_, db0 + d * H1_, ZD0, H1_, IN_);
        colpartial<<<dim3(16, 32), 256, 0, stream>>>(ZD0, H1_, stg(s), stg(s) + 1024);
        bn_relu<<<B_ * H1_ / 4 / 256, 256, 0, stream>>>(ZD0, H1_, stg(s), stg(s) + 1024, dg0 + d * H1_, dbt0 + d * H1_);

        gemm64<<<dim3(64, 8), 256, 0, stream>>>(ZD0, dW1 + (size_t)d * H1_ * H2_, db1 + d * H2_, D1, H2_, H1_);
        colpartial<<<dim3(8, 32), 256, 0, stream>>>(D1, H2_, stg(s + 1), stg(s + 1) + 1024);
        bn_relu<<<B_ * H2_ / 4 / 256, 256, 0, stream>>>(D1, H2_, stg(s + 1), stg(s + 1) + 1024, dg1 + d * H2_, dbt1 + d * H2_);

        adapter_kernel<<<B_, 256, 0, stream>>>(D1, Z1, u0, v0, u1, v1, bl0, bl1, T2);
        colpartial<<<dim3(8, 32), 256, 0, stream>>>(T2, H2_, stg(s + 2), stg(s + 2) + 1024);
        head_kernel<<<B_, 256, 0, stream>>>(T2, D1, stg(s + 2), stg(s + 2) + 1024, g1, b1,
                                            dWo + (size_t)d * H2_, dbo + d, outs + (size_t)d * B_);
    }
    select_kernel<<<(B_ + 255) / 256, 256, 0, stream>>>(x, outs, out);
    (void)in_sizes; (void)n_in; (void)out_size; (void)ws_size;
}

// Round 3
// 497.734 us; speedup vs baseline: 1.9286x; 1.9286x over previous
//
#include <hip/hip_runtime.h>
#include <hip/hip_bf16.h>
#include <math.h>

// Problem constants (fixed by the reference)
#define F_   30
#define E_   16
#define B_   4096
#define IN_  480      // F*E
#define H1_  1024
#define H2_  512
#define K_   32
#define HH_  512
#define D_   3
#define V_   10000
#define EPS_ 1e-5f

typedef __attribute__((ext_vector_type(8))) short bf16x8;   // MFMA A/B frag (8 bf16)
typedef __attribute__((ext_vector_type(4))) float f32x4;    // MFMA C/D frag
typedef __attribute__((ext_vector_type(8))) unsigned short u16x8;

__device__ __forceinline__ unsigned short f2bf(float f) {   // RNE f32->bf16
    unsigned u = __builtin_bit_cast(unsigned, f);
    u += 0x7FFFu + ((u >> 16) & 1u);
    return (unsigned short)(u >> 16);
}
__device__ __forceinline__ float bf2f(unsigned short h) {
    return __builtin_bit_cast(float, ((unsigned)h) << 16);
}
__device__ __forceinline__ void gload_lds16(const unsigned short* g, unsigned short* l) {
    typedef unsigned int __attribute__((address_space(1))) guint;
    typedef unsigned int __attribute__((address_space(3))) luint;
    __builtin_amdgcn_global_load_lds((const guint*)g, (luint*)l, 16, 0, 0);
}

// ---------------------------------------------------------------------------
// embBF[b, f*16+e] = bf16(tables[f, x[f,b], e]); one 16B write per thread
__global__ __launch_bounds__(256) void gather_kernel(const int* __restrict__ x,
                                                     const float* __restrict__ tables,
                                                     unsigned short* __restrict__ emb) {
    int idx = blockIdx.x * 256 + threadIdx.x;          // B_*F_*2 total
    int b = idx / (F_ * 2);
    int r = idx - b * (F_ * 2);
    int f = r >> 1, h = r & 1;
    int row = x[f * B_ + b];
    const float4* src = reinterpret_cast<const float4*>(tables + ((size_t)f * V_ + row) * E_ + h * 8);
    float4 v0 = src[0], v1 = src[1];
    u16x8 o;
    o[0]=f2bf(v0.x); o[1]=f2bf(v0.y); o[2]=f2bf(v0.z); o[3]=f2bf(v0.w);
    o[4]=f2bf(v1.x); o[5]=f2bf(v1.y); o[6]=f2bf(v1.z); o[7]=f2bf(v1.w);
    *reinterpret_cast<u16x8*>(emb + (size_t)b * IN_ + f * E_ + h * 8) = o;
}

// ---------------------------------------------------------------------------
// Fused transpose+convert: W f32 [K][N] -> Wt bf16 [N][K], 9 segments, 32x32 tiles
struct TransArgs {
    const float* src[9];
    unsigned short* dst[9];
    int K[9], N[9], base[9];
};
__global__ __launch_bounds__(256) void transpose_bf16_kernel(TransArgs ta) {
    __shared__ float tile[32][33];
    int blk = blockIdx.x;
    int seg = 0;
#pragma unroll
    for (int i = 1; i < 9; i++) if (blk >= ta.base[i]) seg = i;
    int tix = blk - ta.base[seg];
    int Kd = ta.K[seg], Nd = ta.N[seg];
    int tn = Nd >> 5;
    int k0 = (tix / tn) << 5;
    int n0 = (tix - (tix / tn) * tn) << 5;
    const float* src = ta.src[seg];
    unsigned short* dst = ta.dst[seg];
    int t = threadIdx.x;
    int c = t & 31, rr = t >> 5;
#pragma unroll
    for (int i = 0; i < 4; i++) {
        int r = rr + i * 8;
        tile[r][c] = src[(size_t)(k0 + r) * Nd + n0 + c];
    }
    __syncthreads();
#pragma unroll
    for (int i = 0; i < 4; i++) {
        int r = rr + i * 8;   // n index
        dst[(size_t)(n0 + r) * Kd + k0 + c] = f2bf(tile[c][r]);
    }
}

__global__ __launch_bounds__(256) void convert_bf16_kernel(const float* __restrict__ s,
                                                           unsigned short* __restrict__ d, int n) {
    int i = blockIdx.x * 256 + threadIdx.x;
    if (i < n) d[i] = f2bf(s[i]);
}

// ---------------------------------------------------------------------------
// C[M,N] = A[M,K] @ Bt[N,K]^T  (both bf16, K-contiguous). M=4096. 128x128 tile,
// BK=32, 4 waves (2x2), each wave 64x64 via 4x4 frags of mfma_f32_16x16x32_bf16.
// LDS XOR-swizzle: chunk ^= (row>>1)&3 (16B chunks within 64B rows) -> <=2-way.
__global__ __launch_bounds__(256) void gemm_bf16_128(const unsigned short* __restrict__ A,
                                                     const unsigned short* __restrict__ Bt,
                                                     float* __restrict__ C,
                                                     int N, int K) {
    __shared__ unsigned short sA[128 * 32];
    __shared__ unsigned short sB[128 * 32];
    int tid = threadIdx.x;
    int l = tid & 63, w = tid >> 6;
    int wr = w >> 1, wc = w & 1;
    int bm = blockIdx.x << 7, bn = blockIdx.y << 7;
    const unsigned short* Ab = A + (size_t)bm * K;
    const unsigned short* Bb = Bt + (size_t)bn * K;
    f32x4 acc[4][4] = {};
    int n0c = tid, n1c = tid + 256;
    int r0 = n0c >> 2, lc0 = (n0c & 3) ^ ((r0 >> 1) & 3);
    int r1 = n1c >> 2, lc1 = (n1c & 3) ^ ((r1 >> 1) & 3);
    int kg = l >> 4, lr = l & 15;
    for (int k0 = 0; k0 < K; k0 += 32) {
        gload_lds16(Ab + (size_t)r0 * K + k0 + lc0 * 8, &sA[n0c * 8]);
        gload_lds16(Ab + (size_t)r1 * K + k0 + lc1 * 8, &sA[n1c * 8]);
        gload_lds16(Bb + (size_t)r0 * K + k0 + lc0 * 8, &sB[n0c * 8]);
        gload_lds16(Bb + (size_t)r1 * K + k0 + lc1 * 8, &sB[n1c * 8]);
        __syncthreads();
        bf16x8 af[4], bfr[4];
#pragma unroll
        for (int m = 0; m < 4; m++) {
            int R = (wr << 6) + (m << 4) + lr;
            af[m] = *reinterpret_cast<const bf16x8*>(&sA[R * 32 + ((kg ^ ((R >> 1) & 3)) << 3)]);
        }
#pragma unroll
        for (int n = 0; n < 4; n++) {
            int R = (wc << 6) + (n << 4) + lr;
            bfr[n] = *reinterpret_cast<const bf16x8*>(&sB[R * 32 + ((kg ^ ((R >> 1) & 3)) << 3)]);
        }
#pragma unroll
        for (int m = 0; m < 4; m++)
#pragma unroll
            for (int n = 0; n < 4; n++)
                acc[m][n] = __builtin_amdgcn_mfma_f32_16x16x32_bf16(af[m], bfr[n], acc[m][n], 0, 0, 0);
        __syncthreads();
    }
    int orow = bm + (wr << 6) + (kg << 2);
    int ocol = bn + (wc << 6) + lr;
#pragma unroll
    for (int m = 0; m < 4; m++)
#pragma unroll
        for (int n = 0; n < 4; n++)
#pragma unroll
            for (int j = 0; j < 4; j++)
                C[(size_t)(orow + (m << 4) + j) * N + ocol + (n << 4)] = acc[m][n][j];
}

// ---------------------------------------------------------------------------
// Afac[M,32] = A[M,K] @ Bt[32,K]^T (bf16). BM=128, 4 waves each own 32 rows, 2x2 frags.
__global__ __launch_bounds__(256) void gemm_bf16_N32(const unsigned short* __restrict__ A,
                                                     const unsigned short* __restrict__ Bt,
                                                     float* __restrict__ C,
                                                     int K) {
    __shared__ unsigned short sA[128 * 32];
    __shared__ unsigned short sB[32 * 32];
    int tid = threadIdx.x;
    int l = tid & 63, w = tid >> 6;
    int bm = blockIdx.x << 7;
    const unsigned short* Ab = A + (size_t)bm * K;
    f32x4 acc[2][2] = {};
    int n0c = tid, n1c = tid + 256;
    int r0 = n0c >> 2, lc0 = (n0c & 3) ^ ((r0 >> 1) & 3);
    int r1 = n1c >> 2, lc1 = (n1c & 3) ^ ((r1 >> 1) & 3);
    int kg = l >> 4, lr = l & 15;
    for (int k0 = 0; k0 < K; k0 += 32) {
        gload_lds16(Ab + (size_t)r0 * K + k0 + lc0 * 8, &sA[n0c * 8]);
        gload_lds16(Ab + (size_t)r1 * K + k0 + lc1 * 8, &sA[n1c * 8]);
        if (tid < 128)
            gload_lds16(Bt + (size_t)r0 * K + k0 + lc0 * 8, &sB[n0c * 8]);
        __syncthreads();
        bf16x8 af[2], bfr[2];
#pragma unroll
        for (int m = 0; m < 2; m++) {
            int R = (w << 5) + (m << 4) + lr;
            af[m] = *reinterpret_cast<const bf16x8*>(&sA[R * 32 + ((kg ^ ((R >> 1) & 3)) << 3)]);
        }
#pragma unroll
        for (int n = 0; n < 2; n++) {
            int R = (n << 4) + lr;
            bfr[n] = *reinterpret_cast<const bf16x8*>(&sB[R * 32 + ((kg ^ ((R >> 1) & 3)) << 3)]);
        }
#pragma unroll
        for (int m = 0; m < 2; m++)
#pragma unroll
            for (int n = 0; n < 2; n++)
                acc[m][n] = __builtin_amdgcn_mfma_f32_16x16x32_bf16(af[m], bfr[n], acc[m][n], 0, 0, 0);
        __syncthreads();
    }
    int orow = bm + (w << 5) + (kg << 2);
#pragma unroll
    for (int m = 0; m < 2; m++)
#pragma unroll
        for (int n = 0; n < 2; n++)
#pragma unroll
            for (int j = 0; j < 4; j++)
                C[(size_t)(orow + (m << 4) + j) * 32 + (n << 4) + lr] = acc[m][n][j];
}

// ---------------------------------------------------------------------------
// Partial column sums/sumsq with atomics. Grid: (N/64, 32 slabs of 128 rows).
__global__ __launch_bounds__(256) void colpartial(const float* __restrict__ Z, int N,
                                                  float* __restrict__ colsum,
                                                  float* __restrict__ colsumsq) {
    int lc = threadIdx.x & 63;
    int c  = blockIdx.x * 64 + lc;
    int rg = threadIdx.x >> 6;
    int r0 = blockIdx.y * 128 + rg;
    float s = 0.f, ss = 0.f;
#pragma unroll 8
    for (int k = 0; k < 32; k++) {
        float v = Z[(size_t)(r0 + 4 * k) * N + c];
        s += v; ss += v * v;
    }
    __shared__ float sh[2][4][64];
    sh[0][rg][lc] = s;
    sh[1][rg][lc] = ss;
    __syncthreads();
    if (threadIdx.x < 64) {
        int cc = blockIdx.x * 64 + threadIdx.x;
        float S  = sh[0][0][threadIdx.x] + sh[0][1][threadIdx.x] + sh[0][2][threadIdx.x] + sh[0][3][threadIdx.x];
        float SS = sh[1][0][threadIdx.x] + sh[1][1][threadIdx.x] + sh[1][2][threadIdx.x] + sh[1][3][threadIdx.x];
        atomicAdd(&colsum[cc], S);
        atomicAdd(&colsumsq[cc], SS);
    }
}

// ---------------------------------------------------------------------------
// BN (biased var) + ReLU from Z f32; writes f32 (if of32) and/or bf16 (if obf).
__global__ __launch_bounds__(256) void bn_apply_kernel(const float* __restrict__ Z,
                                                       float* __restrict__ of32,
                                                       unsigned short* __restrict__ obf,
                                                       int N,
                                                       const float* __restrict__ stats,
                                                       const float* __restrict__ g,
                                                       const float* __restrict__ bt) {
    int idx = blockIdx.x * 256 + threadIdx.x;          // over B_*N/8
    int c0 = (idx * 8) & (N - 1);
    float4 v0 = reinterpret_cast<const float4*>(Z)[idx * 2];
    float4 v1 = reinterpret_cast<const float4*>(Z)[idx * 2 + 1];
    float r[8] = {v0.x, v0.y, v0.z, v0.w, v1.x, v1.y, v1.z, v1.w};
#pragma unroll
    for (int q = 0; q < 8; q++) {
        int c = c0 + q;
        float S = stats[c], SS = stats[1024 + c];
        float m = S * (1.f / B_);
        float var = (SS - S * m) * (1.f / B_);
        float rs = rsqrtf(var + EPS_);
        r[q] = fmaxf(0.f, g[c] * (r[q] - m) * rs + bt[c]);
    }
    if (of32) {
        reinterpret_cast<float4*>(of32)[idx * 2]     = make_float4(r[0], r[1], r[2], r[3]);
        reinterpret_cast<float4*>(of32)[idx * 2 + 1] = make_float4(r[4], r[5], r[6], r[7]);
    }
    if (obf) {
        u16x8 o;
#pragma unroll
        for (int q = 0; q < 8; q++) o[q] = f2bf(r[q]);
        *reinterpret_cast<u16x8*>(obf + (size_t)idx * 8) = o;
    }
}

// ---------------------------------------------------------------------------
// Per-row LoRA chain. a = Afac[b] (precomputed D1@u0). c = a@H_b, t = sigmoid(c@v0
// + bl0), a2 = t@u1, c2 = a2@H_b, T2[b] = c2@v1 (bl1 cancels in the following BN).
// One wave per row x 4 rows per wave; v1(bf16), v0, u1 staged in LDS.
__global__ __launch_bounds__(256) void adapter_kernel(const float* __restrict__ Afac,
                                                      const float* __restrict__ H,
                                                      const float* __restrict__ v0,
                                                      const float* __restrict__ u1,
                                                      const float* __restrict__ bl0,
                                                      const unsigned short* __restrict__ v1bf,
                                                      float* __restrict__ T2) {
    __shared__ unsigned short sv1[K_ * H2_];   // 32KB
    __shared__ float sv0[K_ * K_];
    __shared__ float su1[K_ * K_];
    int t = threadIdx.x;
#pragma unroll
    for (int i = 0; i < 8; i++)
        *reinterpret_cast<u16x8*>(&sv1[(i * 256 + t) * 8]) =
            *reinterpret_cast<const u16x8*>(&v1bf[(i * 256 + t) * 8]);
    reinterpret_cast<float4*>(sv0)[t] = reinterpret_cast<const float4*>(v0)[t];
    reinterpret_cast<float4*>(su1)[t] = reinterpret_cast<const float4*>(u1)[t];
    __syncthreads();
    int w = t >> 6, l = t & 63;
    int i = l & 31;
    float bl0i = bl0[i];
    for (int r = 0; r < 4; r++) {
        int b = (blockIdx.x << 4) + (w << 2) + r;
        float a = Afac[b * 32 + i];
        float hreg[32];
#pragma unroll
        for (int k = 0; k < 32; k++) hreg[k] = H[(size_t)b * 1024 + k * 32 + i];
        float c = 0.f;
#pragma unroll
        for (int k = 0; k < 32; k++) c += __shfl(a, k) * hreg[k];
        float targ = bl0i;
#pragma unroll
        for (int k = 0; k < 32; k++) targ += __shfl(c, k) * sv0[k * 32 + i];
        float tv = 1.f / (1.f + expf(-targ));
        float a2 = 0.f;
#pragma unroll
        for (int k = 0; k < 32; k++) a2 += __shfl(tv, k) * su1[k * 32 + i];
        float c2 = 0.f;
#pragma unroll
        for (int k = 0; k < 32; k++) c2 += __shfl(a2, k) * hreg[k];
        float o[8] = {};
#pragma unroll
        for (int k = 0; k < 32; k++) {
            float cb = __shfl(c2, k);
            u16x8 vv = *reinterpret_cast<const u16x8*>(&sv1[k * 512 + l * 8]);
#pragma unroll
            for (int q = 0; q < 8; q++) o[q] += cb * bf2f(vv[q]);
        }
        float4* dst = reinterpret_cast<float4*>(&T2[(size_t)b * 512 + l * 8]);
        dst[0] = make_float4(o[0], o[1], o[2], o[3]);
        dst[1] = make_float4(o[4], o[5], o[6], o[7]);
    }
}

// ---------------------------------------------------------------------------
// Final per-domain head: BN(T2, unbiased) -> + D1 residual -> dot wo -> sigmoid
__global__ __launch_bounds__(256) void head_kernel(const float* __restrict__ T2,
                                                   const unsigned short* __restrict__ D1bf,
                                                   const float* __restrict__ colsum,
                                                   const float* __restrict__ colsumsq,
                                                   const float* __restrict__ g1,
                                                   const float* __restrict__ b1,
                                                   const float* __restrict__ wo,
                                                   const float* __restrict__ bo,
                                                   float* __restrict__ outs) {
    int b = blockIdx.x, t = threadIdx.x;
    float p = 0.f;
#pragma unroll
    for (int q = 0; q < 2; q++) {
        int j = t + q * 256;
        float S = colsum[j], SS = colsumsq[j];
        float m = S * (1.f / B_);
        float var = (SS - S * m) * (1.f / (B_ - 1));
        float rs = rsqrtf(var + EPS_);
        float di = g1[j] * (T2[(size_t)b * H2_ + j] - m) * rs + b1[j] + bf2f(D1bf[(size_t)b * H2_ + j]);
        p += di * wo[j];
    }
    p += __shfl_down(p, 32); p += __shfl_down(p, 16); p += __shfl_down(p, 8);
    p += __shfl_down(p, 4);  p += __shfl_down(p, 2);  p += __shfl_down(p, 1);
    __shared__ float sw[4];
    if ((t & 63) == 0) sw[t >> 6] = p;
    __syncthreads();
    if (t == 0) {
        float logit = sw[0] + sw[1] + sw[2] + sw[3] + bo[0];
        outs[b] = 1.f / (1.f + expf(-logit));
    }
}

__global__ __launch_bounds__(256) void zero_kernel(float* __restrict__ p, int n) {
    int i = blockIdx.x * 256 + threadIdx.x;
    if (i < n) p[i] = 0.f;
}

__global__ __launch_bounds__(256) void select_kernel(const int* __restrict__ x,
                                                     const float* __restrict__ outs,
                                                     float* __restrict__ out) {
    int b = blockIdx.x * 256 + threadIdx.x;
    if (b < B_) {
        int d = x[(F_ - 1) * B_ + b];
        out[b] = outs[(size_t)d * B_ + b];
    }
}

// ---------------------------------------------------------------------------
extern "C" void kernel_launch(void* const* d_in, const int* in_sizes, int n_in,
                              void* d_out, int out_size, void* d_ws, size_t ws_size,
                              hipStream_t stream) {
    const int*   x      = (const int*)  d_in[0];
    const float* tables = (const float*)d_in[1];
    const float* dW0  = (const float*)d_in[2];
    const float* dg0  = (const float*)d_in[4];
    const float* dbt0 = (const float*)d_in[5];
    const float* dW1  = (const float*)d_in[6];
    const float* dg1  = (const float*)d_in[8];
    const float* dbt1 = (const float*)d_in[9];
    const float* dWo  = (const float*)d_in[10];
    const float* dbo  = (const float*)d_in[11];
    const float* hW0  = (const float*)d_in[12];
    const float* hg0  = (const float*)d_in[14];
    const float* hbt0 = (const float*)d_in[15];
    const float* hW1  = (const float*)d_in[16];
    const float* hg1  = (const float*)d_in[18];
    const float* hbt1 = (const float*)d_in[19];
    const float* u0   = (const float*)d_in[20];
    const float* u1   = (const float*)d_in[21];
    const float* v0   = (const float*)d_in[22];
    const float* v1   = (const float*)d_in[23];
    const float* bl0  = (const float*)d_in[24];
    const float* g1   = (const float*)d_in[26];
    const float* b1   = (const float*)d_in[27];
    float* out = (float*)d_out;

    // ---- workspace layout (float units; all 16B aligned) ----
    float* ws    = (float*)d_ws;
    float* stats = ws;                                   // 11 * 2048
    float* outs  = stats + 22528;                        // 3 * 4096
    float* Afac  = outs + 12288;                         // 4096*32
    unsigned short* ACTBF = (unsigned short*)(Afac + 131072);   // max(Z0BF 2M, ZD0BF 4M ush)
    unsigned short* D1BF  = ACTBF + 4194304;             // 4096*512 ush
    unsigned short* embBF = D1BF + 2097152;              // 4096*480 ush
    unsigned short* WBF   = embBF + 1966080;             // 3,850,240 ush total
    unsigned short* hW0t  = WBF;                         // [512][480]
    unsigned short* hW1t  = hW0t + 245760;               // [1024][512]
    unsigned short* dW0t  = hW1t + 524288;               // [3][1024][480]
    unsigned short* dW1t  = dW0t + 1474560;              // [3][512][1024]
    unsigned short* u0t   = dW1t + 1572864;              // [32][512]
    unsigned short* v1bf  = u0t + 16384;                 // [32][512]
    float* Z1  = (float*)(WBF + 3850240);                // hyper f32, 4096*1024
    float* T2  = Z1 + 4194304;                           // 4096*512
    float* SCR = T2 + 2097152;                           // 4096*1024 f32 scratch (pre-BN)
    unsigned short* Z0BF  = ACTBF;                       // 4096*512
    unsigned short* ZD0BF = ACTBF;                       // 4096*1024 (after Z0BF dead)

    auto stg = [&](int s) { return stats + (size_t)s * 2048; };

    zero_kernel<<<88, 256, 0, stream>>>(stats, 11 * 2048);
    gather_kernel<<<960, 256, 0, stream>>>(x, tables, embBF);

    TransArgs ta;
    ta.src[0] = hW0; ta.dst[0] = hW0t; ta.K[0] = 480;  ta.N[0] = 512;
    ta.src[1] = hW1; ta.dst[1] = hW1t; ta.K[1] = 512;  ta.N[1] = 1024;
    for (int d = 0; d < 3; d++) {
        ta.src[2 + d] = dW0 + (size_t)d * 480 * 1024; ta.dst[2 + d] = dW0t + (size_t)d * 1024 * 480;
        ta.K[2 + d] = 480; ta.N[2 + d] = 1024;
        ta.src[5 + d] = dW1 + (size_t)d * 1024 * 512; ta.dst[5 + d] = dW1t + (size_t)d * 512 * 1024;
        ta.K[5 + d] = 1024; ta.N[5 + d] = 512;
    }
    ta.src[8] = u0; ta.dst[8] = u0t; ta.K[8] = 512; ta.N[8] = 32;
    int acc_t = 0;
    for (int i = 0; i < 9; i++) { ta.base[i] = acc_t; acc_t += (ta.K[i] >> 5) * (ta.N[i] >> 5); }
    transpose_bf16_kernel<<<acc_t, 256, 0, stream>>>(ta);       // 3744 blocks
    convert_bf16_kernel<<<64, 256, 0, stream>>>(v1, v1bf, 16384);

    // hyper-net layer 0: [B,480] @ [480,512]   (biases cancel in BN)
    gemm_bf16_128<<<dim3(32, 4), 256, 0, stream>>>(embBF, hW0t, SCR, 512, 480);
    colpartial<<<dim3(8, 32), 256, 0, stream>>>(SCR, 512, stg(0), stg(0) + 1024);
    bn_apply_kernel<<<1024, 256, 0, stream>>>(SCR, nullptr, Z0BF, 512, stg(0), hg0, hbt0);
    // hyper-net layer 1: [B,512] @ [512,1024] -> Z1 (hyper, f32)
    gemm_bf16_128<<<dim3(32, 8), 256, 0, stream>>>(Z0BF, hW1t, Z1, 1024, 512);
    colpartial<<<dim3(16, 32), 256, 0, stream>>>(Z1, 1024, stg(1), stg(1) + 1024);
    bn_apply_kernel<<<2048, 256, 0, stream>>>(Z1, Z1, nullptr, 1024, stg(1), hg1, hbt1);

    for (int d = 0; d < D_; d++) {
        int s = 2 + d * 3;
        gemm_bf16_128<<<dim3(32, 8), 256, 0, stream>>>(embBF, dW0t + (size_t)d * 1024 * 480, SCR, 1024, 480);
        colpartial<<<dim3(16, 32), 256, 0, stream>>>(SCR, 1024, stg(s), stg(s) + 1024);
        bn_apply_kernel<<<2048, 256, 0, stream>>>(SCR, nullptr, ZD0BF, 1024, stg(s), dg0 + d * H1_, dbt0 + d * H1_);

        gemm_bf16_128<<<dim3(32, 4), 256, 0, stream>>>(ZD0BF, dW1t + (size_t)d * 512 * 1024, SCR, 512, 1024);
        colpartial<<<dim3(8, 32), 256, 0, stream>>>(SCR, 512, stg(s + 1), stg(s + 1) + 1024);
        bn_apply_kernel<<<1024, 256, 0, stream>>>(SCR, nullptr, D1BF, 512, stg(s + 1), dg1 + d * H2_, dbt1 + d * H2_);

        gemm_bf16_N32<<<32, 256, 0, stream>>>(D1BF, u0t, Afac, 512);
        adapter_kernel<<<256, 256, 0, stream>>>(Afac, Z1, v0, u1, bl0, v1bf, T2);
        colpartial<<<dim3(8, 32), 256, 0, stream>>>(T2, 512, stg(s + 2), stg(s + 2) + 1024);
        head_kernel<<<4096, 256, 0, stream>>>(T2, D1BF, stg(s + 2), stg(s + 2) + 1024, g1, b1,
                                              dWo + (size_t)d * H2_, dbo + d, outs + (size_t)d * B_);
    }
    select_kernel<<<16, 256, 0, stream>>>(x, outs, out);
    (void)in_sizes; (void)n_in; (void)out_size; (void)ws_size;
}

// Round 4
// 367.776 us; speedup vs baseline: 2.6101x; 1.3534x over previous
//
#include <hip/hip_runtime.h>
#include <hip/hip_bf16.h>
#include <math.h>

// Problem constants (fixed by the reference)
#define F_   30
#define E_   16
#define B_   4096
#define IN_  480      // F*E
#define H1_  1024
#define H2_  512
#define K_   32
#define HH_  512
#define D_   3
#define V_   10000
#define EPS_ 1e-5f

typedef __attribute__((ext_vector_type(8))) short bf16x8;   // MFMA A/B frag (8 bf16)
typedef __attribute__((ext_vector_type(4))) float f32x4;    // MFMA C/D frag
typedef __attribute__((ext_vector_type(8))) unsigned short u16x8;

__device__ __forceinline__ unsigned short f2bf(float f) {   // RNE f32->bf16
    unsigned u = __builtin_bit_cast(unsigned, f);
    u += 0x7FFFu + ((u >> 16) & 1u);
    return (unsigned short)(u >> 16);
}
__device__ __forceinline__ float bf2f(unsigned short h) {
    return __builtin_bit_cast(float, ((unsigned)h) << 16);
}
__device__ __forceinline__ void gload_lds16(const unsigned short* g, unsigned short* l) {
    typedef unsigned int __attribute__((address_space(1))) guint;
    typedef unsigned int __attribute__((address_space(3))) luint;
    __builtin_amdgcn_global_load_lds((const guint*)g, (luint*)l, 16, 0, 0);
}

// ---------------------------------------------------------------------------
// embBF[b, f*16+e] = bf16(tables[f, x[f,b], e]); one 16B write per thread
__global__ __launch_bounds__(256) void gather_kernel(const int* __restrict__ x,
                                                     const float* __restrict__ tables,
                                                     unsigned short* __restrict__ emb) {
    int idx = blockIdx.x * 256 + threadIdx.x;          // B_*F_*2 total
    int b = idx / (F_ * 2);
    int r = idx - b * (F_ * 2);
    int f = r >> 1, h = r & 1;
    int row = x[f * B_ + b];
    const float4* src = reinterpret_cast<const float4*>(tables + ((size_t)f * V_ + row) * E_ + h * 8);
    float4 v0 = src[0], v1 = src[1];
    u16x8 o;
    o[0]=f2bf(v0.x); o[1]=f2bf(v0.y); o[2]=f2bf(v0.z); o[3]=f2bf(v0.w);
    o[4]=f2bf(v1.x); o[5]=f2bf(v1.y); o[6]=f2bf(v1.z); o[7]=f2bf(v1.w);
    *reinterpret_cast<u16x8*>(emb + (size_t)b * IN_ + f * E_ + h * 8) = o;
}

// ---------------------------------------------------------------------------
// Fused transpose+convert: W f32 [K][N] -> Wt bf16 [N][K], 9 segments, 32x32 tiles
struct TransArgs {
    const float* src[9];
    unsigned short* dst[9];
    int K[9], N[9], base[9];
};
__global__ __launch_bounds__(256) void transpose_bf16_kernel(TransArgs ta) {
    __shared__ float tile[32][33];
    int blk = blockIdx.x;
    int seg = 0;
#pragma unroll
    for (int i = 1; i < 9; i++) if (blk >= ta.base[i]) seg = i;
    int tix = blk - ta.base[seg];
    int Kd = ta.K[seg], Nd = ta.N[seg];
    int tn = Nd >> 5;
    int k0 = (tix / tn) << 5;
    int n0 = (tix - (tix / tn) * tn) << 5;
    const float* src = ta.src[seg];
    unsigned short* dst = ta.dst[seg];
    int t = threadIdx.x;
    int c = t & 31, rr = t >> 5;
#pragma unroll
    for (int i = 0; i < 4; i++) {
        int r = rr + i * 8;
        tile[r][c] = src[(size_t)(k0 + r) * Nd + n0 + c];
    }
    __syncthreads();
#pragma unroll
    for (int i = 0; i < 4; i++) {
        int r = rr + i * 8;   // n index
        dst[(size_t)(n0 + r) * Kd + k0 + c] = f2bf(tile[c][r]);
    }
}

__global__ __launch_bounds__(256) void convert_bf16_kernel(const float* __restrict__ s,
                                                           unsigned short* __restrict__ d, int n) {
    int i = blockIdx.x * 256 + threadIdx.x;
    if (i < n) d[i] = f2bf(s[i]);
}

// ---------------------------------------------------------------------------
// Grouped bf16 GEMM: C[M,N] = A[M,K] @ Bt[N,K]^T, M=4096. 128x128 tile, BK=32,
// 4 waves (2x2), 4x4 frags of mfma_f32_16x16x32_bf16. Up to 4 groups per launch.
// Epilogue: writes C f32 AND accumulates per-column sum/sumsq via atomics
// (stats[col], stats[N+col]) so no separate colpartial pass is needed.
struct GemmGroups {
    const unsigned short* A[4];
    const unsigned short* Bt[4];
    float* C[4];
    float* stats[4];
    int N[4], K[4], base[4];
};
__global__ __launch_bounds__(256) void gemm_grouped(GemmGroups p) {
    __shared__ unsigned short sA[128 * 32];
    __shared__ unsigned short sB[128 * 32];
    int blk = blockIdx.x;
    int g = 0;
#pragma unroll
    for (int i = 1; i < 4; i++) if (blk >= p.base[i]) g = i;
    int tix = blk - p.base[g];
    int N = p.N[g], K = p.K[g];
    const unsigned short* A = p.A[g];
    const unsigned short* Bt = p.Bt[g];
    float* C = p.C[g];
    float* stats = p.stats[g];
    int bm = (tix & 31) << 7;
    int bn = (tix >> 5) << 7;

    int tid = threadIdx.x;
    int l = tid & 63, w = tid >> 6;
    int wr = w >> 1, wc = w & 1;
    const unsigned short* Ab = A + (size_t)bm * K;
    const unsigned short* Bb = Bt + (size_t)bn * K;
    f32x4 acc[4][4] = {};
    int n0c = tid, n1c = tid + 256;
    int r0 = n0c >> 2, lc0 = (n0c & 3) ^ ((r0 >> 1) & 3);
    int r1 = n1c >> 2, lc1 = (n1c & 3) ^ ((r1 >> 1) & 3);
    int kg = l >> 4, lr = l & 15;
    for (int k0 = 0; k0 < K; k0 += 32) {
        gload_lds16(Ab + (size_t)r0 * K + k0 + lc0 * 8, &sA[n0c * 8]);
        gload_lds16(Ab + (size_t)r1 * K + k0 + lc1 * 8, &sA[n1c * 8]);
        gload_lds16(Bb + (size_t)r0 * K + k0 + lc0 * 8, &sB[n0c * 8]);
        gload_lds16(Bb + (size_t)r1 * K + k0 + lc1 * 8, &sB[n1c * 8]);
        __syncthreads();
        bf16x8 af[4], bfr[4];
#pragma unroll
        for (int m = 0; m < 4; m++) {
            int R = (wr << 6) + (m << 4) + lr;
            af[m] = *reinterpret_cast<const bf16x8*>(&sA[R * 32 + ((kg ^ ((R >> 1) & 3)) << 3)]);
        }
#pragma unroll
        for (int n = 0; n < 4; n++) {
            int R = (wc << 6) + (n << 4) + lr;
            bfr[n] = *reinterpret_cast<const bf16x8*>(&sB[R * 32 + ((kg ^ ((R >> 1) & 3)) << 3)]);
        }
#pragma unroll
        for (int m = 0; m < 4; m++)
#pragma unroll
            for (int n = 0; n < 4; n++)
                acc[m][n] = __builtin_amdgcn_mfma_f32_16x16x32_bf16(af[m], bfr[n], acc[m][n], 0, 0, 0);
        __syncthreads();
    }
    int orow = bm + (wr << 6) + (kg << 2);
    int ocol = bn + (wc << 6) + lr;
#pragma unroll
    for (int m = 0; m < 4; m++)
#pragma unroll
        for (int n = 0; n < 4; n++)
#pragma unroll
            for (int j = 0; j < 4; j++)
                C[(size_t)(orow + (m << 4) + j) * N + ocol + (n << 4)] = acc[m][n][j];
    // ---- column stats (sum / sumsq over this tile's 64 rows per wave) ----
#pragma unroll
    for (int n = 0; n < 4; n++) {
        float s = 0.f, ss = 0.f;
#pragma unroll
        for (int m = 0; m < 4; m++)
#pragma unroll
            for (int j = 0; j < 4; j++) {
                float v = acc[m][n][j];
                s += v; ss += v * v;
            }
        s  += __shfl_xor(s, 16);  s  += __shfl_xor(s, 32);
        ss += __shfl_xor(ss, 16); ss += __shfl_xor(ss, 32);
        if (l < 16) {
            int col = bn + (wc << 6) + (n << 4) + lr;
            atomicAdd(&stats[col], s);
            atomicAdd(&stats[N + col], ss);
        }
    }
}

// ---------------------------------------------------------------------------
// Afac[d][M,32] = D1[d][M,K] @ u0t[32,K]^T (bf16). z-batched over domains.
__global__ __launch_bounds__(256) void gemm_bf16_N32(const unsigned short* __restrict__ D1BF,
                                                     const unsigned short* __restrict__ Bt,
                                                     float* __restrict__ Afac) {
    __shared__ unsigned short sA[128 * 32];
    __shared__ unsigned short sB[32 * 32];
    int d = blockIdx.y;
    const unsigned short* A = D1BF + (size_t)d * B_ * H2_;
    float* C = Afac + (size_t)d * B_ * 32;
    const int K = 512;
    int tid = threadIdx.x;
    int l = tid & 63, w = tid >> 6;
    int bm = blockIdx.x << 7;
    const unsigned short* Ab = A + (size_t)bm * K;
    f32x4 acc[2][2] = {};
    int n0c = tid, n1c = tid + 256;
    int r0 = n0c >> 2, lc0 = (n0c & 3) ^ ((r0 >> 1) & 3);
    int r1 = n1c >> 2, lc1 = (n1c & 3) ^ ((r1 >> 1) & 3);
    int kg = l >> 4, lr = l & 15;
    for (int k0 = 0; k0 < K; k0 += 32) {
        gload_lds16(Ab + (size_t)r0 * K + k0 + lc0 * 8, &sA[n0c * 8]);
        gload_lds16(Ab + (size_t)r1 * K + k0 + lc1 * 8, &sA[n1c * 8]);
        if (tid < 128)
            gload_lds16(Bt + (size_t)r0 * K + k0 + lc0 * 8, &sB[n0c * 8]);
        __syncthreads();
        bf16x8 af[2], bfr[2];
#pragma unroll
        for (int m = 0; m < 2; m++) {
            int R = (w << 5) + (m << 4) + lr;
            af[m] = *reinterpret_cast<const bf16x8*>(&sA[R * 32 + ((kg ^ ((R >> 1) & 3)) << 3)]);
        }
#pragma unroll
        for (int n = 0; n < 2; n++) {
            int R = (n << 4) + lr;
            bfr[n] = *reinterpret_cast<const bf16x8*>(&sB[R * 32 + ((kg ^ ((R >> 1) & 3)) << 3)]);
        }
#pragma unroll
        for (int m = 0; m < 2; m++)
#pragma unroll
            for (int n = 0; n < 2; n++)
                acc[m][n] = __builtin_amdgcn_mfma_f32_16x16x32_bf16(af[m], bfr[n], acc[m][n], 0, 0, 0);
        __syncthreads();
    }
    int orow = bm + (w << 5) + (kg << 2);
#pragma unroll
    for (int m = 0; m < 2; m++)
#pragma unroll
        for (int n = 0; n < 2; n++)
#pragma unroll
            for (int j = 0; j < 4; j++)
                C[(size_t)(orow + (m << 4) + j) * 32 + (n << 4) + lr] = acc[m][n][j];
}

// ---------------------------------------------------------------------------
// BN(biased)+ReLU for the fused K=480 layer output Z480 [4096][3584].
// cols [0,512) -> hyper0 -> Z0BF; cols [512+d*1024, ...) -> domain d -> ZD0BF[d]
__global__ __launch_bounds__(256) void bn480_kernel(const float* __restrict__ Z480,
                                                    const float* __restrict__ stats,
                                                    const float* __restrict__ hg0,
                                                    const float* __restrict__ hbt0,
                                                    const float* __restrict__ dg0,
                                                    const float* __restrict__ dbt0,
                                                    unsigned short* __restrict__ Z0BF,
                                                    unsigned short* __restrict__ ZD0BF) {
    int idx = blockIdx.x * 256 + threadIdx.x;          // 4096*448
    int b = idx / 448;
    int c0 = (idx - b * 448) * 8;
    const float* g;
    const float* bt;
    unsigned short* dst;
    if (c0 < 512) {
        g = hg0 + c0; bt = hbt0 + c0;
        dst = Z0BF + (size_t)b * 512 + c0;
    } else {
        int d = (c0 - 512) >> 10, cc = (c0 - 512) & 1023;
        g = dg0 + d * 1024 + cc; bt = dbt0 + d * 1024 + cc;
        dst = ZD0BF + ((size_t)d << 22) + (size_t)b * 1024 + cc;
    }
    float4 v0 = reinterpret_cast<const float4*>(Z480 + (size_t)b * 3584 + c0)[0];
    float4 v1 = reinterpret_cast<const float4*>(Z480 + (size_t)b * 3584 + c0)[1];
    float r[8] = {v0.x, v0.y, v0.z, v0.w, v1.x, v1.y, v1.z, v1.w};
    u16x8 o;
#pragma unroll
    for (int q = 0; q < 8; q++) {
        float S = stats[c0 + q], SS = stats[3584 + c0 + q];
        float m = S * (1.f / B_);
        float var = (SS - S * m) * (1.f / B_);
        float rs = rsqrtf(var + EPS_);
        o[q] = f2bf(fmaxf(0.f, g[q] * (r[q] - m) * rs + bt[q]));
    }
    *reinterpret_cast<u16x8*>(dst) = o;
}

// BN+ReLU for hyper layer1: Z1scr [4096][1024] -> Hbf bf16
__global__ __launch_bounds__(256) void bnH_kernel(const float* __restrict__ Z,
                                                  const float* __restrict__ stats,
                                                  const float* __restrict__ g,
                                                  const float* __restrict__ bt,
                                                  unsigned short* __restrict__ out) {
    int idx = blockIdx.x * 256 + threadIdx.x;          // 4096*128
    int c0 = (idx & 127) * 8;
    float4 v0 = reinterpret_cast<const float4*>(Z)[idx * 2];
    float4 v1 = reinterpret_cast<const float4*>(Z)[idx * 2 + 1];
    float r[8] = {v0.x, v0.y, v0.z, v0.w, v1.x, v1.y, v1.z, v1.w};
    u16x8 o;
#pragma unroll
    for (int q = 0; q < 8; q++) {
        float S = stats[c0 + q], SS = stats[1024 + c0 + q];
        float m = S * (1.f / B_);
        float var = (SS - S * m) * (1.f / B_);
        float rs = rsqrtf(var + EPS_);
        o[q] = f2bf(fmaxf(0.f, g[c0 + q] * (r[q] - m) * rs + bt[c0 + q]));
    }
    *reinterpret_cast<u16x8*>(out + (size_t)idx * 8) = o;
}

// BN+ReLU for domain layer1 (batched over 3 domains): SCR1 [3*4096][512] -> D1BF
__global__ __launch_bounds__(256) void bnD1_kernel(const float* __restrict__ Z,
                                                   const float* __restrict__ statsD1,
                                                   const float* __restrict__ dg1,
                                                   const float* __restrict__ dbt1,
                                                   unsigned short* __restrict__ D1BF) {
    int idx = blockIdx.x * 256 + threadIdx.x;          // 12288*64
    int row = idx >> 6;
    int c0 = (idx & 63) * 8;
    int d = row >> 12;
    const float* stats = statsD1 + d * 1024;
    const float* g = dg1 + d * 512;
    const float* bt = dbt1 + d * 512;
    float4 v0 = reinterpret_cast<const float4*>(Z)[idx * 2];
    float4 v1 = reinterpret_cast<const float4*>(Z)[idx * 2 + 1];
    float r[8] = {v0.x, v0.y, v0.z, v0.w, v1.x, v1.y, v1.z, v1.w};
    u16x8 o;
#pragma unroll
    for (int q = 0; q < 8; q++) {
        float S = stats[c0 + q], SS = stats[512 + c0 + q];
        float m = S * (1.f / B_);
        float var = (SS - S * m) * (1.f / B_);
        float rs = rsqrtf(var + EPS_);
        o[q] = f2bf(fmaxf(0.f, g[c0 + q] * (r[q] - m) * rs + bt[c0 + q]));
    }
    *reinterpret_cast<u16x8*>(D1BF + (size_t)idx * 8) = o;
}

// ---------------------------------------------------------------------------
// Per-row LoRA chain for ALL 3 domains (H row loaded once, reused 3x).
// a = Afac[d][b]; c = a@H_b; t = sigmoid(c@v0+bl0); a2 = t@u1; c2 = a2@H_b;
// T2[d][b] = c2@v1 (bl1 cancels in following BN). One wave per row, 4 rows/wave.
__global__ __launch_bounds__(256) void adapter_kernel(const float* __restrict__ Afac,
                                                      const unsigned short* __restrict__ Hbf,
                                                      const float* __restrict__ v0,
                                                      const float* __restrict__ u1,
                                                      const float* __restrict__ bl0,
                                                      const unsigned short* __restrict__ v1bf,
                                                      float* __restrict__ T2) {
    __shared__ unsigned short sv1[K_ * H2_];   // 32KB
    __shared__ float sv0[K_ * K_];
    __shared__ float su1[K_ * K_];
    int t = threadIdx.x;
#pragma unroll
    for (int i = 0; i < 8; i++)
        *reinterpret_cast<u16x8*>(&sv1[(i * 256 + t) * 8]) =
            *reinterpret_cast<const u16x8*>(&v1bf[(i * 256 + t) * 8]);
    reinterpret_cast<float4*>(sv0)[t] = reinterpret_cast<const float4*>(v0)[t];
    reinterpret_cast<float4*>(su1)[t] = reinterpret_cast<const float4*>(u1)[t];
    __syncthreads();
    int w = t >> 6, l = t & 63;
    int i = l & 31;
    float bl0i = bl0[i];
    for (int r = 0; r < 4; r++) {
        int b = (blockIdx.x << 4) + (w << 2) + r;
        float hreg[32];
#pragma unroll
        for (int k = 0; k < 32; k++) hreg[k] = bf2f(Hbf[(size_t)b * 1024 + k * 32 + i]);
#pragma unroll
        for (int d = 0; d < 3; d++) {
            float a = Afac[(size_t)d * 131072 + b * 32 + i];
            float c = 0.f;
#pragma unroll
            for (int k = 0; k < 32; k++) c += __shfl(a, k) * hreg[k];
            float targ = bl0i;
#pragma unroll
            for (int k = 0; k < 32; k++) targ += __shfl(c, k) * sv0[k * 32 + i];
            float tv = 1.f / (1.f + expf(-targ));
            float a2 = 0.f;
#pragma unroll
            for (int k = 0; k < 32; k++) a2 += __shfl(tv, k) * su1[k * 32 + i];
            float c2 = 0.f;
#pragma unroll
            for (int k = 0; k < 32; k++) c2 += __shfl(a2, k) * hreg[k];
            float o[8] = {};
#pragma unroll
            for (int k = 0; k < 32; k++) {
                float cb = __shfl(c2, k);
                u16x8 vv = *reinterpret_cast<const u16x8*>(&sv1[k * 512 + l * 8]);
#pragma unroll
                for (int q = 0; q < 8; q++) o[q] += cb * bf2f(vv[q]);
            }
            float4* dst = reinterpret_cast<float4*>(&T2[(size_t)d * 2097152 + (size_t)b * 512 + l * 8]);
            dst[0] = make_float4(o[0], o[1], o[2], o[3]);
            dst[1] = make_float4(o[4], o[5], o[6], o[7]);
        }
    }
}

// ---------------------------------------------------------------------------
// Column sums/sumsq for T2, z-batched over domains.
__global__ __launch_bounds__(256) void colpartialT2(const float* __restrict__ T2,
                                                    float* __restrict__ statsT2) {
    int z = blockIdx.z;
    const float* Z = T2 + (size_t)z * 2097152;
    float* colsum = statsT2 + z * 1024;
    float* colsumsq = colsum + 512;
    int lc = threadIdx.x & 63;
    int c  = blockIdx.x * 64 + lc;
    int rg = threadIdx.x >> 6;
    int r0 = blockIdx.y * 128 + rg;
    float s = 0.f, ss = 0.f;
#pragma unroll 8
    for (int k = 0; k < 32; k++) {
        float v = Z[(size_t)(r0 + 4 * k) * 512 + c];
        s += v; ss += v * v;
    }
    __shared__ float sh[2][4][64];
    sh[0][rg][lc] = s;
    sh[1][rg][lc] = ss;
    __syncthreads();
    if (threadIdx.x < 64) {
        int cc = blockIdx.x * 64 + threadIdx.x;
        float S  = sh[0][0][threadIdx.x] + sh[0][1][threadIdx.x] + sh[0][2][threadIdx.x] + sh[0][3][threadIdx.x];
        float SS = sh[1][0][threadIdx.x] + sh[1][1][threadIdx.x] + sh[1][2][threadIdx.x] + sh[1][3][threadIdx.x];
        atomicAdd(&colsum[cc], S);
        atomicAdd(&colsumsq[cc], SS);
    }
}

// ---------------------------------------------------------------------------
// Final head, batched over domains: BN(T2, unbiased) + D1 -> dot wo -> sigmoid
__global__ __launch_bounds__(256) void head_kernel(const float* __restrict__ T2,
                                                   const unsigned short* __restrict__ D1BF,
                                                   const float* __restrict__ statsT2,
                                                   const float* __restrict__ g1,
                                                   const float* __restrict__ b1,
                                                   const float* __restrict__ dWo,
                                                   const float* __restrict__ dbo,
                                                   float* __restrict__ outs) {
    int b = blockIdx.x, d = blockIdx.y, t = threadIdx.x;
    const float* T2d = T2 + (size_t)d * 2097152;
    const unsigned short* D1d = D1BF + (size_t)d * 2097152;
    const float* colsum = statsT2 + d * 1024;
    const float* colsumsq = colsum + 512;
    const float* wo = dWo + d * 512;
    float p = 0.f;
#pragma unroll
    for (int q = 0; q < 2; q++) {
        int j = t + q * 256;
        float S = colsum[j], SS = colsumsq[j];
        float m = S * (1.f / B_);
        float var = (SS - S * m) * (1.f / (B_ - 1));
        float rs = rsqrtf(var + EPS_);
        float di = g1[j] * (T2d[(size_t)b * H2_ + j] - m) * rs + b1[j] + bf2f(D1d[(size_t)b * H2_ + j]);
        p += di * wo[j];
    }
    p += __shfl_down(p, 32); p += __shfl_down(p, 16); p += __shfl_down(p, 8);
    p += __shfl_down(p, 4);  p += __shfl_down(p, 2);  p += __shfl_down(p, 1);
    __shared__ float sw[4];
    if ((t & 63) == 0) sw[t >> 6] = p;
    __syncthreads();
    if (t == 0) {
        float logit = sw[0] + sw[1] + sw[2] + sw[3] + dbo[d];
        outs[(size_t)d * B_ + b] = 1.f / (1.f + expf(-logit));
    }
}

__global__ __launch_bounds__(256) void zero_kernel(float* __restrict__ p, int n) {
    int i = blockIdx.x * 256 + threadIdx.x;
    if (i < n) p[i] = 0.f;
}

__global__ __launch_bounds__(256) void select_kernel(const int* __restrict__ x,
                                                     const float* __restrict__ outs,
                                                     float* __restrict__ out) {
    int b = blockIdx.x * 256 + threadIdx.x;
    if (b < B_) {
        int d = x[(F_ - 1) * B_ + b];
        out[b] = outs[(size_t)d * B_ + b];
    }
}

// ---------------------------------------------------------------------------
extern "C" void kernel_launch(void* const* d_in, const int* in_sizes, int n_in,
                              void* d_out, int out_size, void* d_ws, size_t ws_size,
                              hipStream_t stream) {
    const int*   x      = (const int*)  d_in[0];
    const float* tables = (const float*)d_in[1];
    const float* dW0  = (const float*)d_in[2];
    const float* dg0  = (const float*)d_in[4];
    const float* dbt0 = (const float*)d_in[5];
    const float* dW1  = (const float*)d_in[6];
    const float* dg1  = (const float*)d_in[8];
    const float* dbt1 = (const float*)d_in[9];
    const float* dWo  = (const float*)d_in[10];
    const float* dbo  = (const float*)d_in[11];
    const float* hW0  = (const float*)d_in[12];
    const float* hg0  = (const float*)d_in[14];
    const float* hbt0 = (const float*)d_in[15];
    const float* hW1  = (const float*)d_in[16];
    const float* hg1  = (const float*)d_in[18];
    const float* hbt1 = (const float*)d_in[19];
    const float* u0   = (const float*)d_in[20];
    const float* u1   = (const float*)d_in[21];
    const float* v0   = (const float*)d_in[22];
    const float* v1   = (const float*)d_in[23];
    const float* bl0  = (const float*)d_in[24];
    const float* g1   = (const float*)d_in[26];
    const float* b1   = (const float*)d_in[27];
    float* out = (float*)d_out;

    // ---- workspace layout (float units; all 16B aligned) ----
    float* ws       = (float*)d_ws;
    float* stats480 = ws;                        // 2*3584 = 7168
    float* statsH   = stats480 + 7168;           // 2*1024 = 2048
    float* statsD1  = statsH + 2048;             // 3*2*512 = 3072
    float* statsT2  = statsD1 + 3072;            // 3*2*512 = 3072
    float* outs     = statsT2 + 3072;            // 3*4096
    float* Afac     = outs + 12288;              // 3*4096*32
    float* Z480     = Afac + 393216;             // 4096*3584
    float* Z1scr    = Z480 + 14680064;           // 4096*1024
    float* SCR1     = Z1scr + 4194304;           // 3*4096*512
    float* T2       = SCR1 + 6291456;            // 3*4096*512
    unsigned short* embBF = (unsigned short*)(T2 + 6291456);  // 4096*480
    unsigned short* Z0BF  = embBF + 1966080;     // 4096*512
    unsigned short* ZD0BF = Z0BF + 2097152;      // 3*4096*1024
    unsigned short* Hbf   = ZD0BF + 12582912;    // 4096*1024
    unsigned short* D1BF  = Hbf + 4194304;       // 3*4096*512
    unsigned short* W480  = D1BF + 6291456;      // [3584][480]
    unsigned short* hW1t  = W480 + 1720320;      // [1024][512]
    unsigned short* dW1t  = hW1t + 524288;       // [3][512][1024]
    unsigned short* u0t   = dW1t + 1572864;      // [32][512]
    unsigned short* v1bf  = u0t + 16384;         // [32][512]

    zero_kernel<<<60, 256, 0, stream>>>(ws, 15360);
    gather_kernel<<<960, 256, 0, stream>>>(x, tables, embBF);

    TransArgs ta;
    ta.src[0] = hW0; ta.dst[0] = W480; ta.K[0] = 480; ta.N[0] = 512;
    ta.src[1] = hW1; ta.dst[1] = hW1t; ta.K[1] = 512; ta.N[1] = 1024;
    for (int d = 0; d < 3; d++) {
        ta.src[2 + d] = dW0 + (size_t)d * 480 * 1024;
        ta.dst[2 + d] = W480 + (size_t)(512 + d * 1024) * 480;
        ta.K[2 + d] = 480; ta.N[2 + d] = 1024;
        ta.src[5 + d] = dW1 + (size_t)d * 1024 * 512;
        ta.dst[5 + d] = dW1t + (size_t)d * 512 * 1024;
        ta.K[5 + d] = 1024; ta.N[5 + d] = 512;
    }
    ta.src[8] = u0; ta.dst[8] = u0t; ta.K[8] = 512; ta.N[8] = 32;
    int acc_t = 0;
    for (int i = 0; i < 9; i++) { ta.base[i] = acc_t; acc_t += (ta.K[i] >> 5) * (ta.N[i] >> 5); }
    transpose_bf16_kernel<<<acc_t, 256, 0, stream>>>(ta);       // 3744 blocks
    convert_bf16_kernel<<<64, 256, 0, stream>>>(v1, v1bf, 16384);

    // ---- fused K=480 layer: [B,480] @ [480, 512+3*1024] (hyper0 + 3x dW0) ----
    GemmGroups g480;
    g480.A[0] = embBF; g480.Bt[0] = W480; g480.C[0] = Z480;
    g480.stats[0] = stats480; g480.N[0] = 3584; g480.K[0] = 480; g480.base[0] = 0;
    for (int i = 1; i < 4; i++) { g480.base[i] = 0x7fffffff; g480.A[i] = nullptr; g480.Bt[i] = nullptr; g480.C[i] = nullptr; g480.stats[i] = nullptr; g480.N[i] = 0; g480.K[i] = 32; }
    gemm_grouped<<<896, 256, 0, stream>>>(g480);
    bn480_kernel<<<7168, 256, 0, stream>>>(Z480, stats480, hg0, hbt0, dg0, dbt0, Z0BF, ZD0BF);

    // ---- grouped layer-1: hyper1 (N=1024,K=512) + 3x dW1 (N=512,K=1024) ----
    GemmGroups g2;
    g2.A[0] = Z0BF; g2.Bt[0] = hW1t; g2.C[0] = Z1scr;
    g2.stats[0] = statsH; g2.N[0] = 1024; g2.K[0] = 512; g2.base[0] = 0;
    for (int d = 0; d < 3; d++) {
        g2.A[1 + d] = ZD0BF + (size_t)d * 4194304;
        g2.Bt[1 + d] = dW1t + (size_t)d * 524288;
        g2.C[1 + d] = SCR1 + (size_t)d * 2097152;
        g2.stats[1 + d] = statsD1 + d * 1024;
        g2.N[1 + d] = 512; g2.K[1 + d] = 1024;
        g2.base[1 + d] = 256 + d * 128;
    }
    gemm_grouped<<<640, 256, 0, stream>>>(g2);
    bnH_kernel<<<2048, 256, 0, stream>>>(Z1scr, statsH, hg1, hbt1, Hbf);
    bnD1_kernel<<<3072, 256, 0, stream>>>(SCR1, statsD1, dg1, dbt1, D1BF);

    gemm_bf16_N32<<<dim3(32, 3), 256, 0, stream>>>(D1BF, u0t, Afac);
    adapter_kernel<<<256, 256, 0, stream>>>(Afac, Hbf, v0, u1, bl0, v1bf, T2);
    colpartialT2<<<dim3(8, 32, 3), 256, 0, stream>>>(T2, statsT2);
    head_kernel<<<dim3(4096, 3), 256, 0, stream>>>(T2, D1BF, statsT2, g1, b1, dWo, dbo, outs);
    select_kernel<<<16, 256, 0, stream>>>(x, outs, out);
    (void)in_sizes; (void)n_in; (void)out_size; (void)ws_size;
}

// Round 5
// 286.979 us; speedup vs baseline: 3.3450x; 1.2815x over previous
//
#include <hip/hip_runtime.h>
#include <hip/hip_bf16.h>
#include <math.h>

// Problem constants (fixed by the reference)
#define F_   30
#define E_   16
#define B_   4096
#define IN_  480      // F*E
#define H1_  1024
#define H2_  512
#define K_   32
#define HH_  512
#define D_   3
#define V_   10000
#define EPS_ 1e-5f

typedef __attribute__((ext_vector_type(8))) short bf16x8;   // MFMA A/B frag (8 bf16)
typedef __attribute__((ext_vector_type(4))) float f32x4;    // MFMA C/D frag
typedef __attribute__((ext_vector_type(8))) unsigned short u16x8;

__device__ __forceinline__ unsigned short f2bf(float f) {   // RNE f32->bf16
    unsigned u = __builtin_bit_cast(unsigned, f);
    u += 0x7FFFu + ((u >> 16) & 1u);
    return (unsigned short)(u >> 16);
}
__device__ __forceinline__ float bf2f(unsigned short h) {
    return __builtin_bit_cast(float, ((unsigned)h) << 16);
}
__device__ __forceinline__ void gload_lds16(const unsigned short* g, unsigned short* l) {
    typedef unsigned int __attribute__((address_space(1))) guint;
    typedef unsigned int __attribute__((address_space(3))) luint;
    __builtin_amdgcn_global_load_lds((const guint*)g, (luint*)l, 16, 0, 0);
}

// ---------------------------------------------------------------------------
// embBF[b, f*16+e] = bf16(tables[f, x[f,b], e]); one 16B write per thread
__global__ __launch_bounds__(256) void gather_kernel(const int* __restrict__ x,
                                                     const float* __restrict__ tables,
                                                     unsigned short* __restrict__ emb) {
    int idx = blockIdx.x * 256 + threadIdx.x;          // B_*F_*2 total
    int b = idx / (F_ * 2);
    int r = idx - b * (F_ * 2);
    int f = r >> 1, h = r & 1;
    int row = x[f * B_ + b];
    const float4* src = reinterpret_cast<const float4*>(tables + ((size_t)f * V_ + row) * E_ + h * 8);
    float4 v0 = src[0], v1 = src[1];
    u16x8 o;
    o[0]=f2bf(v0.x); o[1]=f2bf(v0.y); o[2]=f2bf(v0.z); o[3]=f2bf(v0.w);
    o[4]=f2bf(v1.x); o[5]=f2bf(v1.y); o[6]=f2bf(v1.z); o[7]=f2bf(v1.w);
    *reinterpret_cast<u16x8*>(emb + (size_t)b * IN_ + f * E_ + h * 8) = o;
}

// ---------------------------------------------------------------------------
// Fused transpose+convert: W f32 [K][N] -> Wt bf16 [N][K], 9 segments, 32x32 tiles
struct TransArgs {
    const float* src[9];
    unsigned short* dst[9];
    int K[9], N[9], base[9];
};
__global__ __launch_bounds__(256) void transpose_bf16_kernel(TransArgs ta) {
    __shared__ float tile[32][33];
    int blk = blockIdx.x;
    int seg = 0;
#pragma unroll
    for (int i = 1; i < 9; i++) if (blk >= ta.base[i]) seg = i;
    int tix = blk - ta.base[seg];
    int Kd = ta.K[seg], Nd = ta.N[seg];
    int tn = Nd >> 5;
    int k0 = (tix / tn) << 5;
    int n0 = (tix - (tix / tn) * tn) << 5;
    const float* src = ta.src[seg];
    unsigned short* dst = ta.dst[seg];
    int t = threadIdx.x;
    int c = t & 31, rr = t >> 5;
#pragma unroll
    for (int i = 0; i < 4; i++) {
        int r = rr + i * 8;
        tile[r][c] = src[(size_t)(k0 + r) * Nd + n0 + c];
    }
    __syncthreads();
#pragma unroll
    for (int i = 0; i < 4; i++) {
        int r = rr + i * 8;   // n index
        dst[(size_t)(n0 + r) * Kd + k0 + c] = f2bf(tile[c][r]);
    }
}

__global__ __launch_bounds__(256) void convert_bf16_kernel(const float* __restrict__ s,
                                                           unsigned short* __restrict__ d, int n) {
    int i = blockIdx.x * 256 + threadIdx.x;
    if (i < n) d[i] = f2bf(s[i]);
}

// ---------------------------------------------------------------------------
// Grouped bf16 GEMM: C[M,N] = A[M,K] @ Bt[N,K]^T, M=4096. 128x128 tile, BK=32,
// 4 waves (2x2), 4x4 frags of mfma_f32_16x16x32_bf16. Up to 4 groups per launch.
// Epilogue: writes C (f32 or bf16 per obf flag) AND accumulates per-column
// sum/sumsq (from f32 accumulators) via atomics -> no separate colpartial pass.
struct GemmGroups {
    const unsigned short* A[4];
    const unsigned short* Bt[4];
    void* C[4];
    float* stats[4];
    int N[4], K[4], base[4], obf[4];
};
__global__ __launch_bounds__(256) void gemm_grouped(GemmGroups p) {
    __shared__ unsigned short sA[128 * 32];
    __shared__ unsigned short sB[128 * 32];
    int blk = blockIdx.x;
    int g = 0;
#pragma unroll
    for (int i = 1; i < 4; i++) if (blk >= p.base[i]) g = i;
    int tix = blk - p.base[g];
    int N = p.N[g], K = p.K[g];
    const unsigned short* A = p.A[g];
    const unsigned short* Bt = p.Bt[g];
    float* stats = p.stats[g];
    int bm = (tix & 31) << 7;
    int bn = (tix >> 5) << 7;

    int tid = threadIdx.x;
    int l = tid & 63, w = tid >> 6;
    int wr = w >> 1, wc = w & 1;
    const unsigned short* Ab = A + (size_t)bm * K;
    const unsigned short* Bb = Bt + (size_t)bn * K;
    f32x4 acc[4][4] = {};
    int n0c = tid, n1c = tid + 256;
    int r0 = n0c >> 2, lc0 = (n0c & 3) ^ ((r0 >> 1) & 3);
    int r1 = n1c >> 2, lc1 = (n1c & 3) ^ ((r1 >> 1) & 3);
    int kg = l >> 4, lr = l & 15;
    for (int k0 = 0; k0 < K; k0 += 32) {
        gload_lds16(Ab + (size_t)r0 * K + k0 + lc0 * 8, &sA[n0c * 8]);
        gload_lds16(Ab + (size_t)r1 * K + k0 + lc1 * 8, &sA[n1c * 8]);
        gload_lds16(Bb + (size_t)r0 * K + k0 + lc0 * 8, &sB[n0c * 8]);
        gload_lds16(Bb + (size_t)r1 * K + k0 + lc1 * 8, &sB[n1c * 8]);
        __syncthreads();
        bf16x8 af[4], bfr[4];
#pragma unroll
        for (int m = 0; m < 4; m++) {
            int R = (wr << 6) + (m << 4) + lr;
            af[m] = *reinterpret_cast<const bf16x8*>(&sA[R * 32 + ((kg ^ ((R >> 1) & 3)) << 3)]);
        }
#pragma unroll
        for (int n = 0; n < 4; n++) {
            int R = (wc << 6) + (n << 4) + lr;
            bfr[n] = *reinterpret_cast<const bf16x8*>(&sB[R * 32 + ((kg ^ ((R >> 1) & 3)) << 3)]);
        }
#pragma unroll
        for (int m = 0; m < 4; m++)
#pragma unroll
            for (int n = 0; n < 4; n++)
                acc[m][n] = __builtin_amdgcn_mfma_f32_16x16x32_bf16(af[m], bfr[n], acc[m][n], 0, 0, 0);
        __syncthreads();
    }
    int orow = bm + (wr << 6) + (kg << 2);
    int ocol = bn + (wc << 6) + lr;
    if (p.obf[g]) {
        unsigned short* Cb = (unsigned short*)p.C[g];
#pragma unroll
        for (int m = 0; m < 4; m++)
#pragma unroll
            for (int n = 0; n < 4; n++)
#pragma unroll
                for (int j = 0; j < 4; j++)
                    Cb[(size_t)(orow + (m << 4) + j) * N + ocol + (n << 4)] = f2bf(acc[m][n][j]);
    } else {
        float* C = (float*)p.C[g];
#pragma unroll
        for (int m = 0; m < 4; m++)
#pragma unroll
            for (int n = 0; n < 4; n++)
#pragma unroll
                for (int j = 0; j < 4; j++)
                    C[(size_t)(orow + (m << 4) + j) * N + ocol + (n << 4)] = acc[m][n][j];
    }
    // ---- column stats (sum / sumsq over this tile's 64 rows per wave) ----
#pragma unroll
    for (int n = 0; n < 4; n++) {
        float s = 0.f, ss = 0.f;
#pragma unroll
        for (int m = 0; m < 4; m++)
#pragma unroll
            for (int j = 0; j < 4; j++) {
                float v = acc[m][n][j];
                s += v; ss += v * v;
            }
        s  += __shfl_xor(s, 16);  s  += __shfl_xor(s, 32);
        ss += __shfl_xor(ss, 16); ss += __shfl_xor(ss, 32);
        if (l < 16) {
            int col = bn + (wc << 6) + (n << 4) + lr;
            atomicAdd(&stats[col], s);
            atomicAdd(&stats[N + col], ss);
        }
    }
}

// ---------------------------------------------------------------------------
// Afac[d][M,32] = D1[d][M,K] @ u0t[32,K]^T (bf16). z-batched over domains.
__global__ __launch_bounds__(256) void gemm_bf16_N32(const unsigned short* __restrict__ D1BF,
                                                     const unsigned short* __restrict__ Bt,
                                                     float* __restrict__ Afac) {
    __shared__ unsigned short sA[128 * 32];
    __shared__ unsigned short sB[32 * 32];
    int d = blockIdx.y;
    const unsigned short* A = D1BF + (size_t)d * B_ * H2_;
    float* C = Afac + (size_t)d * B_ * 32;
    const int K = 512;
    int tid = threadIdx.x;
    int l = tid & 63, w = tid >> 6;
    int bm = blockIdx.x << 7;
    const unsigned short* Ab = A + (size_t)bm * K;
    f32x4 acc[2][2] = {};
    int n0c = tid, n1c = tid + 256;
    int r0 = n0c >> 2, lc0 = (n0c & 3) ^ ((r0 >> 1) & 3);
    int r1 = n1c >> 2, lc1 = (n1c & 3) ^ ((r1 >> 1) & 3);
    int kg = l >> 4, lr = l & 15;
    for (int k0 = 0; k0 < K; k0 += 32) {
        gload_lds16(Ab + (size_t)r0 * K + k0 + lc0 * 8, &sA[n0c * 8]);
        gload_lds16(Ab + (size_t)r1 * K + k0 + lc1 * 8, &sA[n1c * 8]);
        if (tid < 128)
            gload_lds16(Bt + (size_t)r0 * K + k0 + lc0 * 8, &sB[n0c * 8]);
        __syncthreads();
        bf16x8 af[2], bfr[2];
#pragma unroll
        for (int m = 0; m < 2; m++) {
            int R = (w << 5) + (m << 4) + lr;
            af[m] = *reinterpret_cast<const bf16x8*>(&sA[R * 32 + ((kg ^ ((R >> 1) & 3)) << 3)]);
        }
#pragma unroll
        for (int n = 0; n < 2; n++) {
            int R = (n << 4) + lr;
            bfr[n] = *reinterpret_cast<const bf16x8*>(&sB[R * 32 + ((kg ^ ((R >> 1) & 3)) << 3)]);
        }
#pragma unroll
        for (int m = 0; m < 2; m++)
#pragma unroll
            for (int n = 0; n < 2; n++)
                acc[m][n] = __builtin_amdgcn_mfma_f32_16x16x32_bf16(af[m], bfr[n], acc[m][n], 0, 0, 0);
        __syncthreads();
    }
    int orow = bm + (w << 5) + (kg << 2);
#pragma unroll
    for (int m = 0; m < 2; m++)
#pragma unroll
        for (int n = 0; n < 2; n++)
#pragma unroll
            for (int j = 0; j < 4; j++)
                C[(size_t)(orow + (m << 4) + j) * 32 + (n << 4) + lr] = acc[m][n][j];
}

// ---------------------------------------------------------------------------
// BN(biased)+ReLU for the fused K=480 layer output Z480bf [4096][3584] (bf16 in).
// cols [0,512) -> hyper0 -> Z0BF; cols [512+d*1024, ...) -> domain d -> ZD0BF[d]
__global__ __launch_bounds__(256) void bn480_kernel(const unsigned short* __restrict__ Z480bf,
                                                    const float* __restrict__ stats,
                                                    const float* __restrict__ hg0,
                                                    const float* __restrict__ hbt0,
                                                    const float* __restrict__ dg0,
                                                    const float* __restrict__ dbt0,
                                                    unsigned short* __restrict__ Z0BF,
                                                    unsigned short* __restrict__ ZD0BF) {
    int idx = blockIdx.x * 256 + threadIdx.x;          // 4096*448
    int b = idx / 448;
    int c0 = (idx - b * 448) * 8;
    const float* g;
    const float* bt;
    unsigned short* dst;
    if (c0 < 512) {
        g = hg0 + c0; bt = hbt0 + c0;
        dst = Z0BF + (size_t)b * 512 + c0;
    } else {
        int d = (c0 - 512) >> 10, cc = (c0 - 512) & 1023;
        g = dg0 + d * 1024 + cc; bt = dbt0 + d * 1024 + cc;
        dst = ZD0BF + ((size_t)d << 22) + (size_t)b * 1024 + cc;
    }
    u16x8 v = *reinterpret_cast<const u16x8*>(Z480bf + (size_t)b * 3584 + c0);
    u16x8 o;
#pragma unroll
    for (int q = 0; q < 8; q++) {
        float S = stats[c0 + q], SS = stats[3584 + c0 + q];
        float m = S * (1.f / B_);
        float var = (SS - S * m) * (1.f / B_);
        float rs = rsqrtf(var + EPS_);
        o[q] = f2bf(fmaxf(0.f, g[q] * (bf2f(v[q]) - m) * rs + bt[q]));
    }
    *reinterpret_cast<u16x8*>(dst) = o;
}

// ---------------------------------------------------------------------------
// Merged BN+ReLU for layer-1 outputs (f32 in, bf16 out):
//  blocks [0,2048):   hyper H: Z1scr [4096][1024] -> Hbf
//  blocks [2048,5120): domains: SCR1 [3*4096][512] -> D1BF
__global__ __launch_bounds__(256) void bn_l1_kernel(const float* __restrict__ Z1scr,
                                                    const float* __restrict__ SCR1,
                                                    const float* __restrict__ statsH,
                                                    const float* __restrict__ statsD1,
                                                    const float* __restrict__ hg1,
                                                    const float* __restrict__ hbt1,
                                                    const float* __restrict__ dg1,
                                                    const float* __restrict__ dbt1,
                                                    unsigned short* __restrict__ Hbf,
                                                    unsigned short* __restrict__ D1BF) {
    int gidx = blockIdx.x * 256 + threadIdx.x;
    const float* Z; const float* stats; const float* g; const float* bt;
    unsigned short* outp; int c0; int idx;
    if (gidx < 524288) {               // H: 4096*128
        idx = gidx;
        c0 = (idx & 127) * 8;
        Z = Z1scr; stats = statsH; g = hg1; bt = hbt1; outp = Hbf;
    } else {                           // D1: 12288*64
        idx = gidx - 524288;
        int row = idx >> 6;
        int d = row >> 12;
        c0 = (idx & 63) * 8;
        Z = SCR1; stats = statsD1 + d * 1024; g = dg1 + d * 512; bt = dbt1 + d * 512; outp = D1BF;
    }
    int sh = (gidx < 524288) ? 1024 : 512;
    float4 v0 = reinterpret_cast<const float4*>(Z)[(size_t)idx * 2];
    float4 v1 = reinterpret_cast<const float4*>(Z)[(size_t)idx * 2 + 1];
    float r[8] = {v0.x, v0.y, v0.z, v0.w, v1.x, v1.y, v1.z, v1.w};
    u16x8 o;
#pragma unroll
    for (int q = 0; q < 8; q++) {
        float S = stats[c0 + q], SS = stats[sh + c0 + q];
        float m = S * (1.f / B_);
        float var = (SS - S * m) * (1.f / B_);
        float rs = rsqrtf(var + EPS_);
        o[q] = f2bf(fmaxf(0.f, g[c0 + q] * (r[q] - m) * rs + bt[c0 + q]));
    }
    *reinterpret_cast<u16x8*>(outp + (size_t)idx * 8) = o;
}

// ---------------------------------------------------------------------------
// Adapter core: one wave per batch row, all 3 domains. hreg = H column (32 VGPR).
// a = Afac[d][b]; c = a@H_b; t = sigmoid(c@v0+bl0); a2 = t@u1; c2 = a2@H_b -> C2.
__global__ __launch_bounds__(256) void adapter_core(const float* __restrict__ Afac,
                                                    const unsigned short* __restrict__ Hbf,
                                                    const float* __restrict__ v0,
                                                    const float* __restrict__ u1,
                                                    const float* __restrict__ bl0,
                                                    float* __restrict__ C2) {
    __shared__ float sv0[K_ * K_];
    __shared__ float su1[K_ * K_];
    int t = threadIdx.x;
    reinterpret_cast<float4*>(sv0)[t] = reinterpret_cast<const float4*>(v0)[t];
    reinterpret_cast<float4*>(su1)[t] = reinterpret_cast<const float4*>(u1)[t];
    __syncthreads();
    int w = t >> 6, l = t & 63;
    int i = l & 31;
    int b = blockIdx.x * 4 + w;
    float hreg[32];
#pragma unroll
    for (int k = 0; k < 32; k++) hreg[k] = bf2f(Hbf[(size_t)b * 1024 + k * 32 + i]);
    float bl0i = bl0[i];
#pragma unroll
    for (int d = 0; d < 3; d++) {
        float a = Afac[(size_t)d * 131072 + b * 32 + i];
        float c = 0.f;
#pragma unroll
        for (int k = 0; k < 32; k++) c += __shfl(a, k) * hreg[k];
        float targ = bl0i;
#pragma unroll
        for (int k = 0; k < 32; k++) targ += __shfl(c, k) * sv0[k * 32 + i];
        float tv = 1.f / (1.f + expf(-targ));
        float a2 = 0.f;
#pragma unroll
        for (int k = 0; k < 32; k++) a2 += __shfl(tv, k) * su1[k * 32 + i];
        float c2 = 0.f;
#pragma unroll
        for (int k = 0; k < 32; k++) c2 += __shfl(a2, k) * hreg[k];
        if (l < 32) C2[(size_t)d * 131072 + b * 32 + i] = c2;
    }
}

// ---------------------------------------------------------------------------
// T2[d][b][512] = C2[d][b][32] @ v1 (bf16 v1 in LDS; bl1 cancels in BN).
// One wave per (d,b) row; lane covers 8 columns.
__global__ __launch_bounds__(256) void t2_expand(const float* __restrict__ C2,
                                                 const unsigned short* __restrict__ v1bf,
                                                 float* __restrict__ T2) {
    __shared__ unsigned short sv1[K_ * H2_];   // 32KB
    int t = threadIdx.x;
#pragma unroll
    for (int i2 = 0; i2 < 8; i2++)
        *reinterpret_cast<u16x8*>(&sv1[(i2 * 256 + t) * 8]) =
            *reinterpret_cast<const u16x8*>(&v1bf[(i2 * 256 + t) * 8]);
    __syncthreads();
    int w = t >> 6, l = t & 63;
    int idx = blockIdx.x * 4 + w;              // d*4096 + b
    float cv = C2[(size_t)idx * 32 + (l & 31)];
    float o[8] = {};
#pragma unroll
    for (int k = 0; k < 32; k++) {
        float cb = __shfl(cv, k);
        u16x8 vv = *reinterpret_cast<const u16x8*>(&sv1[k * 512 + l * 8]);
#pragma unroll
        for (int q = 0; q < 8; q++) o[q] += cb * bf2f(vv[q]);
    }
    float4* dst = reinterpret_cast<float4*>(&T2[(size_t)idx * 512 + l * 8]);
    dst[0] = make_float4(o[0], o[1], o[2], o[3]);
    dst[1] = make_float4(o[4], o[5], o[6], o[7]);
}

// ---------------------------------------------------------------------------
// Column sums/sumsq for T2, z-batched over domains.
__global__ __launch_bounds__(256) void colpartialT2(const float* __restrict__ T2,
                                                    float* __restrict__ statsT2) {
    int z = blockIdx.z;
    const float* Z = T2 + (size_t)z * 2097152;
    float* colsum = statsT2 + z * 1024;
    float* colsumsq = colsum + 512;
    int lc = threadIdx.x & 63;
    int c  = blockIdx.x * 64 + lc;
    int rg = threadIdx.x >> 6;
    int r0 = blockIdx.y * 128 + rg;
    float s = 0.f, ss = 0.f;
#pragma unroll 8
    for (int k = 0; k < 32; k++) {
        float v = Z[(size_t)(r0 + 4 * k) * 512 + c];
        s += v; ss += v * v;
    }
    __shared__ float sh[2][4][64];
    sh[0][rg][lc] = s;
    sh[1][rg][lc] = ss;
    __syncthreads();
    if (threadIdx.x < 64) {
        int cc = blockIdx.x * 64 + threadIdx.x;
        float S  = sh[0][0][threadIdx.x] + sh[0][1][threadIdx.x] + sh[0][2][threadIdx.x] + sh[0][3][threadIdx.x];
        float SS = sh[1][0][threadIdx.x] + sh[1][1][threadIdx.x] + sh[1][2][threadIdx.x] + sh[1][3][threadIdx.x];
        atomicAdd(&colsum[cc], S);
        atomicAdd(&colsumsq[cc], SS);
    }
}

// ---------------------------------------------------------------------------
// Final head fused with domain select: d = x[-1][b]; BN(T2,unbiased)+D1 -> wo -> sigmoid
__global__ __launch_bounds__(256) void head_kernel(const int* __restrict__ x,
                                                   const float* __restrict__ T2,
                                                   const unsigned short* __restrict__ D1BF,
                                                   const float* __restrict__ statsT2,
                                                   const float* __restrict__ g1,
                                                   const float* __restrict__ b1,
                                                   const float* __restrict__ dWo,
                                                   const float* __restrict__ dbo,
                                                   float* __restrict__ out) {
    int b = blockIdx.x, t = threadIdx.x;
    int d = x[(F_ - 1) * B_ + b];
    const float* T2d = T2 + (size_t)d * 2097152;
    const unsigned short* D1d = D1BF + (size_t)d * 2097152;
    const float* colsum = statsT2 + d * 1024;
    const float* colsumsq = colsum + 512;
    const float* wo = dWo + d * 512;
    float p = 0.f;
#pragma unroll
    for (int q = 0; q < 2; q++) {
        int j = t + q * 256;
        float S = colsum[j], SS = colsumsq[j];
        float m = S * (1.f / B_);
        float var = (SS - S * m) * (1.f / (B_ - 1));
        float rs = rsqrtf(var + EPS_);
        float di = g1[j] * (T2d[(size_t)b * H2_ + j] - m) * rs + b1[j] + bf2f(D1d[(size_t)b * H2_ + j]);
        p += di * wo[j];
    }
    p += __shfl_down(p, 32); p += __shfl_down(p, 16); p += __shfl_down(p, 8);
    p += __shfl_down(p, 4);  p += __shfl_down(p, 2);  p += __shfl_down(p, 1);
    __shared__ float sw[4];
    if ((t & 63) == 0) sw[t >> 6] = p;
    __syncthreads();
    if (t == 0) {
        float logit = sw[0] + sw[1] + sw[2] + sw[3] + dbo[d];
        out[b] = 1.f / (1.f + expf(-logit));
    }
}

__global__ __launch_bounds__(256) void zero_kernel(float* __restrict__ p, int n) {
    int i = blockIdx.x * 256 + threadIdx.x;
    if (i < n) p[i] = 0.f;
}

// ---------------------------------------------------------------------------
extern "C" void kernel_launch(void* const* d_in, const int* in_sizes, int n_in,
                              void* d_out, int out_size, void* d_ws, size_t ws_size,
                              hipStream_t stream) {
    const int*   x      = (const int*)  d_in[0];
    const float* tables = (const float*)d_in[1];
    const float* dW0  = (const float*)d_in[2];
    const float* dg0  = (const float*)d_in[4];
    const float* dbt0 = (const float*)d_in[5];
    const float* dW1  = (const float*)d_in[6];
    const float* dg1  = (const float*)d_in[8];
    const float* dbt1 = (const float*)d_in[9];
    const float* dWo  = (const float*)d_in[10];
    const float* dbo  = (const float*)d_in[11];
    const float* hW0  = (const float*)d_in[12];
    const float* hg0  = (const float*)d_in[14];
    const float* hbt0 = (const float*)d_in[15];
    const float* hW1  = (const float*)d_in[16];
    const float* hg1  = (const float*)d_in[18];
    const float* hbt1 = (const float*)d_in[19];
    const float* u0   = (const float*)d_in[20];
    const float* u1   = (const float*)d_in[21];
    const float* v0   = (const float*)d_in[22];
    const float* v1   = (const float*)d_in[23];
    const float* bl0  = (const float*)d_in[24];
    const float* g1   = (const float*)d_in[26];
    const float* b1   = (const float*)d_in[27];
    float* out = (float*)d_out;

    // ---- workspace layout (all 16B aligned) ----
    float* ws       = (float*)d_ws;
    float* stats480 = ws;                        // 2*3584 = 7168
    float* statsH   = stats480 + 7168;           // 2*1024 = 2048
    float* statsD1  = statsH + 2048;             // 3*2*512 = 3072
    float* statsT2  = statsD1 + 3072;            // 3*2*512 = 3072
    float* Afac     = statsT2 + 3072;            // 3*4096*32
    float* C2       = Afac + 393216;             // 3*4096*32
    float* Z1scr    = C2 + 393216;               // 4096*1024
    float* SCR1     = Z1scr + 4194304;           // 3*4096*512
    float* T2       = SCR1 + 6291456;            // 3*4096*512
    unsigned short* Z480bf = (unsigned short*)(T2 + 6291456);  // 4096*3584
    unsigned short* embBF = Z480bf + 14680064;   // 4096*480
    unsigned short* Z0BF  = embBF + 1966080;     // 4096*512
    unsigned short* ZD0BF = Z0BF + 2097152;      // 3*4096*1024
    unsigned short* Hbf   = ZD0BF + 12582912;    // 4096*1024
    unsigned short* D1BF  = Hbf + 4194304;       // 3*4096*512
    unsigned short* W480  = D1BF + 6291456;      // [3584][480]
    unsigned short* hW1t  = W480 + 1720320;      // [1024][512]
    unsigned short* dW1t  = hW1t + 524288;       // [3][512][1024]
    unsigned short* u0t   = dW1t + 1572864;      // [32][512]
    unsigned short* v1bf  = u0t + 16384;         // [32][512]

    zero_kernel<<<60, 256, 0, stream>>>(ws, 15360);
    gather_kernel<<<960, 256, 0, stream>>>(x, tables, embBF);

    TransArgs ta;
    ta.src[0] = hW0; ta.dst[0] = W480; ta.K[0] = 480; ta.N[0] = 512;
    ta.src[1] = hW1; ta.dst[1] = hW1t; ta.K[1] = 512; ta.N[1] = 1024;
    for (int d = 0; d < 3; d++) {
        ta.src[2 + d] = dW0 + (size_t)d * 480 * 1024;
        ta.dst[2 + d] = W480 + (size_t)(512 + d * 1024) * 480;
        ta.K[2 + d] = 480; ta.N[2 + d] = 1024;
        ta.src[5 + d] = dW1 + (size_t)d * 1024 * 512;
        ta.dst[5 + d] = dW1t + (size_t)d * 512 * 1024;
        ta.K[5 + d] = 1024; ta.N[5 + d] = 512;
    }
    ta.src[8] = u0; ta.dst[8] = u0t; ta.K[8] = 512; ta.N[8] = 32;
    int acc_t = 0;
    for (int i = 0; i < 9; i++) { ta.base[i] = acc_t; acc_t += (ta.K[i] >> 5) * (ta.N[i] >> 5); }
    transpose_bf16_kernel<<<acc_t, 256, 0, stream>>>(ta);       // 3744 blocks
    convert_bf16_kernel<<<64, 256, 0, stream>>>(v1, v1bf, 16384);

    // ---- fused K=480 layer: [B,480] @ [480, 512+3*1024] -> Z480bf (bf16) ----
    GemmGroups g480;
    g480.A[0] = embBF; g480.Bt[0] = W480; g480.C[0] = Z480bf;
    g480.stats[0] = stats480; g480.N[0] = 3584; g480.K[0] = 480; g480.base[0] = 0; g480.obf[0] = 1;
    for (int i = 1; i < 4; i++) { g480.base[i] = 0x7fffffff; g480.A[i] = nullptr; g480.Bt[i] = nullptr; g480.C[i] = nullptr; g480.stats[i] = nullptr; g480.N[i] = 0; g480.K[i] = 32; g480.obf[i] = 0; }
    gemm_grouped<<<896, 256, 0, stream>>>(g480);
    bn480_kernel<<<7168, 256, 0, stream>>>(Z480bf, stats480, hg0, hbt0, dg0, dbt0, Z0BF, ZD0BF);

    // ---- grouped layer-1: hyper1 (N=1024,K=512) + 3x dW1 (N=512,K=1024), f32 out ----
    GemmGroups g2;
    g2.A[0] = Z0BF; g2.Bt[0] = hW1t; g2.C[0] = Z1scr;
    g2.stats[0] = statsH; g2.N[0] = 1024; g2.K[0] = 512; g2.base[0] = 0; g2.obf[0] = 0;
    for (int d = 0; d < 3; d++) {
        g2.A[1 + d] = ZD0BF + (size_t)d * 4194304;
        g2.Bt[1 + d] = dW1t + (size_t)d * 524288;
        g2.C[1 + d] = SCR1 + (size_t)d * 2097152;
        g2.stats[1 + d] = statsD1 + d * 1024;
        g2.N[1 + d] = 512; g2.K[1 + d] = 1024;
        g2.base[1 + d] = 256 + d * 128;
        g2.obf[1 + d] = 0;
    }
    gemm_grouped<<<640, 256, 0, stream>>>(g2);
    bn_l1_kernel<<<5120, 256, 0, stream>>>(Z1scr, SCR1, statsH, statsD1, hg1, hbt1, dg1, dbt1, Hbf, D1BF);

    gemm_bf16_N32<<<dim3(32, 3), 256, 0, stream>>>(D1BF, u0t, Afac);
    adapter_core<<<1024, 256, 0, stream>>>(Afac, Hbf, v0, u1, bl0, C2);
    t2_expand<<<3072, 256, 0, stream>>>(C2, v1bf, T2);
    colpartialT2<<<dim3(8, 32, 3), 256, 0, stream>>>(T2, statsT2);
    head_kernel<<<4096, 256, 0, stream>>>(x, T2, D1BF, statsT2, g1, b1, dWo, dbo, out);
    (void)in_sizes; (void)n_in; (void)out_size; (void)ws_size;
}

// Round 6
// 283.856 us; speedup vs baseline: 3.3818x; 1.0110x over previous
//
#include <hip/hip_runtime.h>
#include <hip/hip_bf16.h>
#include <math.h>

// Problem constants (fixed by the reference)
#define F_   30
#define E_   16
#define B_   4096
#define IN_  480      // F*E
#define H1_  1024
#define H2_  512
#define K_   32
#define HH_  512
#define D_   3
#define V_   10000
#define EPS_ 1e-5f

typedef __attribute__((ext_vector_type(8))) short bf16x8;   // MFMA A/B frag (8 bf16)
typedef __attribute__((ext_vector_type(4))) float f32x4;    // MFMA C/D frag
typedef __attribute__((ext_vector_type(8))) unsigned short u16x8;

__device__ __forceinline__ unsigned short f2bf(float f) {   // RNE f32->bf16
    unsigned u = __builtin_bit_cast(unsigned, f);
    u += 0x7FFFu + ((u >> 16) & 1u);
    return (unsigned short)(u >> 16);
}
__device__ __forceinline__ float bf2f(unsigned short h) {
    return __builtin_bit_cast(float, ((unsigned)h) << 16);
}
__device__ __forceinline__ void gload_lds16(const unsigned short* g, unsigned short* l) {
    typedef unsigned int __attribute__((address_space(1))) guint;
    typedef unsigned int __attribute__((address_space(3))) luint;
    __builtin_amdgcn_global_load_lds((const guint*)g, (luint*)l, 16, 0, 0);
}

// ---------------------------------------------------------------------------
// Merged prep: [0,ZB) zero stats | [ZB,ZB+960) gather | transpose | convert v1
struct TransArgs {
    const float* src[9];
    unsigned short* dst[9];
    int K[9], N[9], base[9];
};
#define PREP_ZB   73
#define PREP_GA   (PREP_ZB + 960)        // 1033
#define PREP_TR   (PREP_GA + 3744)       // 4777
#define PREP_CV   (PREP_TR + 64)         // 4841
__global__ __launch_bounds__(256) void prep_kernel(TransArgs ta,
                                                   float* __restrict__ zero_p, int zero_n,
                                                   const int* __restrict__ x,
                                                   const float* __restrict__ tables,
                                                   unsigned short* __restrict__ emb,
                                                   const float* __restrict__ v1,
                                                   unsigned short* __restrict__ v1bf) {
    __shared__ float tile[32][33];
    int blk = blockIdx.x;
    int t = threadIdx.x;
    if (blk < PREP_ZB) {
        int i = blk * 256 + t;
        if (i < zero_n) zero_p[i] = 0.f;
    } else if (blk < PREP_GA) {
        int idx = (blk - PREP_ZB) * 256 + t;       // B_*F_*2 total
        int b = idx / (F_ * 2);
        int r = idx - b * (F_ * 2);
        int f = r >> 1, h = r & 1;
        int row = x[f * B_ + b];
        const float4* src = reinterpret_cast<const float4*>(tables + ((size_t)f * V_ + row) * E_ + h * 8);
        float4 v0 = src[0], v1v = src[1];
        u16x8 o;
        o[0]=f2bf(v0.x); o[1]=f2bf(v0.y); o[2]=f2bf(v0.z); o[3]=f2bf(v0.w);
        o[4]=f2bf(v1v.x); o[5]=f2bf(v1v.y); o[6]=f2bf(v1v.z); o[7]=f2bf(v1v.w);
        *reinterpret_cast<u16x8*>(emb + (size_t)b * IN_ + f * E_ + h * 8) = o;
    } else if (blk < PREP_TR) {
        int gblk = blk - PREP_GA;
        int seg = 0;
#pragma unroll
        for (int i = 1; i < 9; i++) if (gblk >= ta.base[i]) seg = i;
        int tix = gblk - ta.base[seg];
        int Kd = ta.K[seg], Nd = ta.N[seg];
        int tn = Nd >> 5;
        int k0 = (tix / tn) << 5;
        int n0 = (tix - (tix / tn) * tn) << 5;
        const float* src = ta.src[seg];
        unsigned short* dst = ta.dst[seg];
        int c = t & 31, rr = t >> 5;
#pragma unroll
        for (int i = 0; i < 4; i++) {
            int r = rr + i * 8;
            tile[r][c] = src[(size_t)(k0 + r) * Nd + n0 + c];
        }
        __syncthreads();
#pragma unroll
        for (int i = 0; i < 4; i++) {
            int r = rr + i * 8;   // n index
            dst[(size_t)(n0 + r) * Kd + k0 + c] = f2bf(tile[c][r]);
        }
    } else {
        int i = (blk - PREP_TR) * 256 + t;
        if (i < K_ * H2_) v1bf[i] = f2bf(v1[i]);
    }
}

// ---------------------------------------------------------------------------
// Grouped bf16 GEMM: C[M,N] = A[M,K] @ Bt[N,K]^T, M=4096. 128x128 tile, BK=32,
// 4 waves (2x2), 4x4 frags of mfma_f32_16x16x32_bf16. Up to 4 groups per launch.
// Epilogue: writes C (f32 or bf16 per obf flag) AND accumulates per-column
// sum/sumsq (from f32 accumulators) via atomics -> no separate colpartial pass.
struct GemmGroups {
    const unsigned short* A[4];
    const unsigned short* Bt[4];
    void* C[4];
    float* stats[4];
    int N[4], K[4], base[4], obf[4];
};
__global__ __launch_bounds__(256) void gemm_grouped(GemmGroups p) {
    __shared__ unsigned short sA[128 * 32];
    __shared__ unsigned short sB[128 * 32];
    int blk = blockIdx.x;
    int g = 0;
#pragma unroll
    for (int i = 1; i < 4; i++) if (blk >= p.base[i]) g = i;
    int tix = blk - p.base[g];
    int N = p.N[g], K = p.K[g];
    const unsigned short* A = p.A[g];
    const unsigned short* Bt = p.Bt[g];
    float* stats = p.stats[g];
    int bm = (tix & 31) << 7;
    int bn = (tix >> 5) << 7;

    int tid = threadIdx.x;
    int l = tid & 63, w = tid >> 6;
    int wr = w >> 1, wc = w & 1;
    const unsigned short* Ab = A + (size_t)bm * K;
    const unsigned short* Bb = Bt + (size_t)bn * K;
    f32x4 acc[4][4] = {};
    int n0c = tid, n1c = tid + 256;
    int r0 = n0c >> 2, lc0 = (n0c & 3) ^ ((r0 >> 1) & 3);
    int r1 = n1c >> 2, lc1 = (n1c & 3) ^ ((r1 >> 1) & 3);
    int kg = l >> 4, lr = l & 15;
    for (int k0 = 0; k0 < K; k0 += 32) {
        gload_lds16(Ab + (size_t)r0 * K + k0 + lc0 * 8, &sA[n0c * 8]);
        gload_lds16(Ab + (size_t)r1 * K + k0 + lc1 * 8, &sA[n1c * 8]);
        gload_lds16(Bb + (size_t)r0 * K + k0 + lc0 * 8, &sB[n0c * 8]);
        gload_lds16(Bb + (size_t)r1 * K + k0 + lc1 * 8, &sB[n1c * 8]);
        __syncthreads();
        bf16x8 af[4], bfr[4];
#pragma unroll
        for (int m = 0; m < 4; m++) {
            int R = (wr << 6) + (m << 4) + lr;
            af[m] = *reinterpret_cast<const bf16x8*>(&sA[R * 32 + ((kg ^ ((R >> 1) & 3)) << 3)]);
        }
#pragma unroll
        for (int n = 0; n < 4; n++) {
            int R = (wc << 6) + (n << 4) + lr;
            bfr[n] = *reinterpret_cast<const bf16x8*>(&sB[R * 32 + ((kg ^ ((R >> 1) & 3)) << 3)]);
        }
#pragma unroll
        for (int m = 0; m < 4; m++)
#pragma unroll
            for (int n = 0; n < 4; n++)
                acc[m][n] = __builtin_amdgcn_mfma_f32_16x16x32_bf16(af[m], bfr[n], acc[m][n], 0, 0, 0);
        __syncthreads();
    }
    int orow = bm + (wr << 6) + (kg << 2);
    int ocol = bn + (wc << 6) + lr;
    if (p.obf[g]) {
        unsigned short* Cb = (unsigned short*)p.C[g];
#pragma unroll
        for (int m = 0; m < 4; m++)
#pragma unroll
            for (int n = 0; n < 4; n++)
#pragma unroll
                for (int j = 0; j < 4; j++)
                    Cb[(size_t)(orow + (m << 4) + j) * N + ocol + (n << 4)] = f2bf(acc[m][n][j]);
    } else {
        float* C = (float*)p.C[g];
#pragma unroll
        for (int m = 0; m < 4; m++)
#pragma unroll
            for (int n = 0; n < 4; n++)
#pragma unroll
                for (int j = 0; j < 4; j++)
                    C[(size_t)(orow + (m << 4) + j) * N + ocol + (n << 4)] = acc[m][n][j];
    }
    // ---- column stats (sum / sumsq over this tile's 64 rows per wave) ----
#pragma unroll
    for (int n = 0; n < 4; n++) {
        float s = 0.f, ss = 0.f;
#pragma unroll
        for (int m = 0; m < 4; m++)
#pragma unroll
            for (int j = 0; j < 4; j++) {
                float v = acc[m][n][j];
                s += v; ss += v * v;
            }
        s  += __shfl_xor(s, 16);  s  += __shfl_xor(s, 32);
        ss += __shfl_xor(ss, 16); ss += __shfl_xor(ss, 32);
        if (l < 16) {
            int col = bn + (wc << 6) + (n << 4) + lr;
            atomicAdd(&stats[col], s);
            atomicAdd(&stats[N + col], ss);
        }
    }
}

// ---------------------------------------------------------------------------
// Afac[d][M,32] = D1[d][M,K] @ u0t[32,K]^T (bf16). z-batched over domains.
__global__ __launch_bounds__(256) void gemm_bf16_N32(const unsigned short* __restrict__ D1BF,
                                                     const unsigned short* __restrict__ Bt,
                                                     float* __restrict__ Afac) {
    __shared__ unsigned short sA[128 * 32];
    __shared__ unsigned short sB[32 * 32];
    int d = blockIdx.y;
    const unsigned short* A = D1BF + (size_t)d * B_ * H2_;
    float* C = Afac + (size_t)d * B_ * 32;
    const int K = 512;
    int tid = threadIdx.x;
    int l = tid & 63, w = tid >> 6;
    int bm = blockIdx.x << 7;
    const unsigned short* Ab = A + (size_t)bm * K;
    f32x4 acc[2][2] = {};
    int n0c = tid, n1c = tid + 256;
    int r0 = n0c >> 2, lc0 = (n0c & 3) ^ ((r0 >> 1) & 3);
    int r1 = n1c >> 2, lc1 = (n1c & 3) ^ ((r1 >> 1) & 3);
    int kg = l >> 4, lr = l & 15;
    for (int k0 = 0; k0 < K; k0 += 32) {
        gload_lds16(Ab + (size_t)r0 * K + k0 + lc0 * 8, &sA[n0c * 8]);
        gload_lds16(Ab + (size_t)r1 * K + k0 + lc1 * 8, &sA[n1c * 8]);
        if (tid < 128)
            gload_lds16(Bt + (size_t)r0 * K + k0 + lc0 * 8, &sB[n0c * 8]);
        __syncthreads();
        bf16x8 af[2], bfr[2];
#pragma unroll
        for (int m = 0; m < 2; m++) {
            int R = (w << 5) + (m << 4) + lr;
            af[m] = *reinterpret_cast<const bf16x8*>(&sA[R * 32 + ((kg ^ ((R >> 1) & 3)) << 3)]);
        }
#pragma unroll
        for (int n = 0; n < 2; n++) {
            int R = (n << 4) + lr;
            bfr[n] = *reinterpret_cast<const bf16x8*>(&sB[R * 32 + ((kg ^ ((R >> 1) & 3)) << 3)]);
        }
#pragma unroll
        for (int m = 0; m < 2; m++)
#pragma unroll
            for (int n = 0; n < 2; n++)
                acc[m][n] = __builtin_amdgcn_mfma_f32_16x16x32_bf16(af[m], bfr[n], acc[m][n], 0, 0, 0);
        __syncthreads();
    }
    int orow = bm + (w << 5) + (kg << 2);
#pragma unroll
    for (int m = 0; m < 2; m++)
#pragma unroll
        for (int n = 0; n < 2; n++)
#pragma unroll
            for (int j = 0; j < 4; j++)
                C[(size_t)(orow + (m << 4) + j) * 32 + (n << 4) + lr] = acc[m][n][j];
}

// ---------------------------------------------------------------------------
// BN(biased)+ReLU for the fused K=480 layer output Z480bf [4096][3584] (bf16 in).
// cols [0,512) -> hyper0 -> Z0BF; cols [512+d*1024, ...) -> domain d -> ZD0BF[d]
__global__ __launch_bounds__(256) void bn480_kernel(const unsigned short* __restrict__ Z480bf,
                                                    const float* __restrict__ stats,
                                                    const float* __restrict__ hg0,
                                                    const float* __restrict__ hbt0,
                                                    const float* __restrict__ dg0,
                                                    const float* __restrict__ dbt0,
                                                    unsigned short* __restrict__ Z0BF,
                                                    unsigned short* __restrict__ ZD0BF) {
    int idx = blockIdx.x * 256 + threadIdx.x;          // 4096*448
    int b = idx / 448;
    int c0 = (idx - b * 448) * 8;
    const float* g;
    const float* bt;
    unsigned short* dst;
    if (c0 < 512) {
        g = hg0 + c0; bt = hbt0 + c0;
        dst = Z0BF + (size_t)b * 512 + c0;
    } else {
        int d = (c0 - 512) >> 10, cc = (c0 - 512) & 1023;
        g = dg0 + d * 1024 + cc; bt = dbt0 + d * 1024 + cc;
        dst = ZD0BF + ((size_t)d << 22) + (size_t)b * 1024 + cc;
    }
    u16x8 v = *reinterpret_cast<const u16x8*>(Z480bf + (size_t)b * 3584 + c0);
    u16x8 o;
#pragma unroll
    for (int q = 0; q < 8; q++) {
        float S = stats[c0 + q], SS = stats[3584 + c0 + q];
        float m = S * (1.f / B_);
        float var = (SS - S * m) * (1.f / B_);
        float rs = rsqrtf(var + EPS_);
        o[q] = f2bf(fmaxf(0.f, g[q] * (bf2f(v[q]) - m) * rs + bt[q]));
    }
    *reinterpret_cast<u16x8*>(dst) = o;
}

// ---------------------------------------------------------------------------
// Merged BN+ReLU for layer-1 outputs (f32 in, bf16 out):
//  blocks [0,2048):   hyper H: Z1scr [4096][1024] -> Hbf
//  blocks [2048,5120): domains: SCR1 [3*4096][512] -> D1BF
__global__ __launch_bounds__(256) void bn_l1_kernel(const float* __restrict__ Z1scr,
                                                    const float* __restrict__ SCR1,
                                                    const float* __restrict__ statsH,
                                                    const float* __restrict__ statsD1,
                                                    const float* __restrict__ hg1,
                                                    const float* __restrict__ hbt1,
                                                    const float* __restrict__ dg1,
                                                    const float* __restrict__ dbt1,
                                                    unsigned short* __restrict__ Hbf,
                                                    unsigned short* __restrict__ D1BF) {
    int gidx = blockIdx.x * 256 + threadIdx.x;
    const float* Z; const float* stats; const float* g; const float* bt;
    unsigned short* outp; int c0; int idx;
    if (gidx < 524288) {               // H: 4096*128
        idx = gidx;
        c0 = (idx & 127) * 8;
        Z = Z1scr; stats = statsH; g = hg1; bt = hbt1; outp = Hbf;
    } else {                           // D1: 12288*64
        idx = gidx - 524288;
        int row = idx >> 6;
        int d = row >> 12;
        c0 = (idx & 63) * 8;
        Z = SCR1; stats = statsD1 + d * 1024; g = dg1 + d * 512; bt = dbt1 + d * 512; outp = D1BF;
    }
    int sh = (gidx < 524288) ? 1024 : 512;
    float4 v0 = reinterpret_cast<const float4*>(Z)[(size_t)idx * 2];
    float4 v1 = reinterpret_cast<const float4*>(Z)[(size_t)idx * 2 + 1];
    float r[8] = {v0.x, v0.y, v0.z, v0.w, v1.x, v1.y, v1.z, v1.w};
    u16x8 o;
#pragma unroll
    for (int q = 0; q < 8; q++) {
        float S = stats[c0 + q], SS = stats[sh + c0 + q];
        float m = S * (1.f / B_);
        float var = (SS - S * m) * (1.f / B_);
        float rs = rsqrtf(var + EPS_);
        o[q] = f2bf(fmaxf(0.f, g[c0 + q] * (r[q] - m) * rs + bt[c0 + q]));
    }
    *reinterpret_cast<u16x8*>(outp + (size_t)idx * 8) = o;
}

// ---------------------------------------------------------------------------
// Adapter core: one wave per batch row, all 3 domains. hreg = H column (32 VGPR).
// a = Afac[d][b]; c = a@H_b; t = sigmoid(c@v0+bl0); a2 = t@u1; c2 = a2@H_b -> C2.
__global__ __launch_bounds__(256) void adapter_core(const float* __restrict__ Afac,
                                                    const unsigned short* __restrict__ Hbf,
                                                    const float* __restrict__ v0,
                                                    const float* __restrict__ u1,
                                                    const float* __restrict__ bl0,
                                                    float* __restrict__ C2) {
    __shared__ float sv0[K_ * K_];
    __shared__ float su1[K_ * K_];
    int t = threadIdx.x;
    reinterpret_cast<float4*>(sv0)[t] = reinterpret_cast<const float4*>(v0)[t];
    reinterpret_cast<float4*>(su1)[t] = reinterpret_cast<const float4*>(u1)[t];
    __syncthreads();
    int w = t >> 6, l = t & 63;
    int i = l & 31;
    int b = blockIdx.x * 4 + w;
    float hreg[32];
#pragma unroll
    for (int k = 0; k < 32; k++) hreg[k] = bf2f(Hbf[(size_t)b * 1024 + k * 32 + i]);
    float bl0i = bl0[i];
#pragma unroll
    for (int d = 0; d < 3; d++) {
        float a = Afac[(size_t)d * 131072 + b * 32 + i];
        float c = 0.f;
#pragma unroll
        for (int k = 0; k < 32; k++) c += __shfl(a, k) * hreg[k];
        float targ = bl0i;
#pragma unroll
        for (int k = 0; k < 32; k++) targ += __shfl(c, k) * sv0[k * 32 + i];
        float tv = 1.f / (1.f + expf(-targ));
        float a2 = 0.f;
#pragma unroll
        for (int k = 0; k < 32; k++) a2 += __shfl(tv, k) * su1[k * 32 + i];
        float c2 = 0.f;
#pragma unroll
        for (int k = 0; k < 32; k++) c2 += __shfl(a2, k) * hreg[k];
        if (l < 32) C2[(size_t)d * 131072 + b * 32 + i] = c2;
    }
}

// ---------------------------------------------------------------------------
// Gram: per domain, M = C2^T C2 (32x32) and s = colsum(C2), atomics over 16 row-blocks.
__global__ __launch_bounds__(256) void gram_kernel(const float* __restrict__ C2,
                                                   float* __restrict__ gramM,
                                                   float* __restrict__ gramS) {
    __shared__ float sc[256 * 32];     // 32KB
    int z = blockIdx.y;
    const float* Cz = C2 + (size_t)z * 131072 + (size_t)blockIdx.x * 256 * 32;
    int t = threadIdx.x;
#pragma unroll
    for (int i = 0; i < 8; i++)
        reinterpret_cast<float4*>(sc)[t + i * 256] = reinterpret_cast<const float4*>(Cz)[t + i * 256];
    __syncthreads();
    int k = t >> 3, k4 = (t & 7) << 2;
    float m0 = 0.f, m1 = 0.f, m2 = 0.f, m3 = 0.f;
    for (int r = 0; r < 256; r++) {
        float ck = sc[r * 32 + k];
        m0 += ck * sc[r * 32 + k4 + 0];
        m1 += ck * sc[r * 32 + k4 + 1];
        m2 += ck * sc[r * 32 + k4 + 2];
        m3 += ck * sc[r * 32 + k4 + 3];
    }
    float* Mz = gramM + z * 1024 + k * 32 + k4;
    atomicAdd(&Mz[0], m0); atomicAdd(&Mz[1], m1);
    atomicAdd(&Mz[2], m2); atomicAdd(&Mz[3], m3);
    if (t < 32) {
        float s = 0.f;
        for (int r = 0; r < 256; r++) s += sc[r * 32 + t];
        atomicAdd(&gramS[z * 32 + t], s);
    }
}

// ---------------------------------------------------------------------------
// statsT2[z][j] = s_z . v1[:,j]; statsT2[z][512+j] = v1[:,j]^T M_z v1[:,j]
__global__ __launch_bounds__(256) void stats_t2_kernel(const float* __restrict__ gramM,
                                                       const float* __restrict__ gramS,
                                                       const unsigned short* __restrict__ v1bf,
                                                       float* __restrict__ statsT2) {
    __shared__ float sM[1024];
    __shared__ float sS[32];
    __shared__ unsigned short sv1[K_ * H2_];   // 32KB
    int z = blockIdx.x;
    int t = threadIdx.x;
    reinterpret_cast<float4*>(sM)[t] = reinterpret_cast<const float4*>(gramM + z * 1024)[t];
    if (t < 8) reinterpret_cast<float4*>(sS)[t] = reinterpret_cast<const float4*>(gramS + z * 32)[t];
#pragma unroll
    for (int i = 0; i < 8; i++)
        reinterpret_cast<u16x8*>(sv1)[t + i * 256] = reinterpret_cast<const u16x8*>(v1bf)[t + i * 256];
    __syncthreads();
#pragma unroll
    for (int jj = 0; jj < 2; jj++) {
        int j = t + jj * 256;
        float vj[32];
#pragma unroll
        for (int k = 0; k < 32; k++) vj[k] = bf2f(sv1[k * 512 + j]);
        float cs = 0.f, ssq = 0.f;
#pragma unroll
        for (int k = 0; k < 32; k++) {
            float wk = 0.f;
#pragma unroll
            for (int kp = 0; kp < 32; kp++) wk += sM[k * 32 + kp] * vj[kp];
            ssq += vj[k] * wk;
            cs += sS[k] * vj[k];
        }
        statsT2[z * 1024 + j] = cs;
        statsT2[z * 1024 + 512 + j] = ssq;
    }
}

// ---------------------------------------------------------------------------
// Head: per row b, d = x[-1][b]; T2 row computed on the fly from C2 row + v1;
// BN(unbiased) + D1 residual -> dot wo -> sigmoid. One wave per row, 4 rows/block.
__global__ __launch_bounds__(256) void head_kernel(const int* __restrict__ x,
                                                   const float* __restrict__ C2,
                                                   const unsigned short* __restrict__ D1BF,
                                                   const float* __restrict__ statsT2,
                                                   const float* __restrict__ g1,
                                                   const float* __restrict__ b1,
                                                   const float* __restrict__ dWo,
                                                   const float* __restrict__ dbo,
                                                   const unsigned short* __restrict__ v1bf,
                                                   float* __restrict__ out) {
    __shared__ unsigned short sv1[K_ * H2_];   // 32KB
    int t = threadIdx.x;
#pragma unroll
    for (int i = 0; i < 8; i++)
        reinterpret_cast<u16x8*>(sv1)[t + i * 256] = reinterpret_cast<const u16x8*>(v1bf)[t + i * 256];
    __syncthreads();
    int w = t >> 6, l = t & 63;
    int b = blockIdx.x * 4 + w;
    int d = x[(F_ - 1) * B_ + b];
    float cv = C2[((size_t)d * B_ + b) * 32 + (l & 31)];
    float o[8] = {};
#pragma unroll
    for (int k = 0; k < 32; k++) {
        float cb = __shfl(cv, k);
        u16x8 vv = *reinterpret_cast<const u16x8*>(&sv1[k * 512 + l * 8]);
#pragma unroll
        for (int q = 0; q < 8; q++) o[q] += cb * bf2f(vv[q]);
    }
    int j0 = l * 8;
    const float* cs = statsT2 + d * 1024;
    float4 Sa = *reinterpret_cast<const float4*>(cs + j0);
    float4 Sb = *reinterpret_cast<const float4*>(cs + j0 + 4);
    float4 Qa = *reinterpret_cast<const float4*>(cs + 512 + j0);
    float4 Qb = *reinterpret_cast<const float4*>(cs + 512 + j0 + 4);
    float4 Ga = *reinterpret_cast<const float4*>(g1 + j0);
    float4 Gb = *reinterpret_cast<const float4*>(g1 + j0 + 4);
    float4 Ba = *reinterpret_cast<const float4*>(b1 + j0);
    float4 Bb = *reinterpret_cast<const float4*>(b1 + j0 + 4);
    float4 Wa = *reinterpret_cast<const float4*>(dWo + d * 512 + j0);
    float4 Wb = *reinterpret_cast<const float4*>(dWo + d * 512 + j0 + 4);
    u16x8 d1v = *reinterpret_cast<const u16x8*>(D1BF + (size_t)d * 2097152 + (size_t)b * 512 + j0);
    float Sv[8] = {Sa.x,Sa.y,Sa.z,Sa.w,Sb.x,Sb.y,Sb.z,Sb.w};
    float Qv[8] = {Qa.x,Qa.y,Qa.z,Qa.w,Qb.x,Qb.y,Qb.z,Qb.w};
    float Gv[8] = {Ga.x,Ga.y,Ga.z,Ga.w,Gb.x,Gb.y,Gb.z,Gb.w};
    float Bv[8] = {Ba.x,Ba.y,Ba.z,Ba.w,Bb.x,Bb.y,Bb.z,Bb.w};
    float Wv[8] = {Wa.x,Wa.y,Wa.z,Wa.w,Wb.x,Wb.y,Wb.z,Wb.w};
    float p = 0.f;
#pragma unroll
    for (int q = 0; q < 8; q++) {
        float S = Sv[q], SS = Qv[q];
        float m = S * (1.f / B_);
        float var = (SS - S * m) * (1.f / (B_ - 1));
        float rs = rsqrtf(var + EPS_);
        float di = Gv[q] * (o[q] - m) * rs + Bv[q] + bf2f(d1v[q]);
        p += di * Wv[q];
    }
    p += __shfl_down(p, 32); p += __shfl_down(p, 16); p += __shfl_down(p, 8);
    p += __shfl_down(p, 4);  p += __shfl_down(p, 2);  p += __shfl_down(p, 1);
    if (l == 0) out[b] = 1.f / (1.f + expf(-(p + dbo[d])));
}

// ---------------------------------------------------------------------------
extern "C" void kernel_launch(void* const* d_in, const int* in_sizes, int n_in,
                              void* d_out, int out_size, void* d_ws, size_t ws_size,
                              hipStream_t stream) {
    const int*   x      = (const int*)  d_in[0];
    const float* tables = (const float*)d_in[1];
    const float* dW0  = (const float*)d_in[2];
    const float* dg0  = (const float*)d_in[4];
    const float* dbt0 = (const float*)d_in[5];
    const float* dW1  = (const float*)d_in[6];
    const float* dg1  = (const float*)d_in[8];
    const float* dbt1 = (const float*)d_in[9];
    const float* dWo  = (const float*)d_in[10];
    const float* dbo  = (const float*)d_in[11];
    const float* hW0  = (const float*)d_in[12];
    const float* hg0  = (const float*)d_in[14];
    const float* hbt0 = (const float*)d_in[15];
    const float* hW1  = (const float*)d_in[16];
    const float* hg1  = (const float*)d_in[18];
    const float* hbt1 = (const float*)d_in[19];
    const float* u0   = (const float*)d_in[20];
    const float* u1   = (const float*)d_in[21];
    const float* v0   = (const float*)d_in[22];
    const float* v1   = (const float*)d_in[23];
    const float* bl0  = (const float*)d_in[24];
    const float* g1   = (const float*)d_in[26];
    const float* b1   = (const float*)d_in[27];
    float* out = (float*)d_out;

    // ---- workspace layout (all 16B aligned) ----
    float* ws       = (float*)d_ws;
    float* stats480 = ws;                        // 7168
    float* statsH   = stats480 + 7168;           // 2048
    float* statsD1  = statsH + 2048;             // 3*1024 = 3072
    float* statsT2  = statsD1 + 3072;            // 3*1024 = 3072
    float* gramM    = statsT2 + 3072;            // 3*1024 = 3072
    float* gramS    = gramM + 3072;              // 128
    // zero region ends at 18560 floats
    float* Afac     = ws + 18560;                // 3*4096*32
    float* C2       = Afac + 393216;             // 3*4096*32
    float* Z1scr    = C2 + 393216;               // 4096*1024
    float* SCR1     = Z1scr + 4194304;           // 3*4096*512
    unsigned short* Z480bf = (unsigned short*)(SCR1 + 6291456);  // 4096*3584
    unsigned short* embBF = Z480bf + 14680064;   // 4096*480
    unsigned short* Z0BF  = embBF + 1966080;     // 4096*512
    unsigned short* ZD0BF = Z0BF + 2097152;      // 3*4096*1024
    unsigned short* Hbf   = ZD0BF + 12582912;    // 4096*1024
    unsigned short* D1BF  = Hbf + 4194304;       // 3*4096*512
    unsigned short* W480  = D1BF + 6291456;      // [3584][480]
    unsigned short* hW1t  = W480 + 1720320;      // [1024][512]
    unsigned short* dW1t  = hW1t + 524288;       // [3][512][1024]
    unsigned short* u0t   = dW1t + 1572864;      // [32][512]
    unsigned short* v1bf  = u0t + 16384;         // [32][512]

    TransArgs ta;
    ta.src[0] = hW0; ta.dst[0] = W480; ta.K[0] = 480; ta.N[0] = 512;
    ta.src[1] = hW1; ta.dst[1] = hW1t; ta.K[1] = 512; ta.N[1] = 1024;
    for (int d = 0; d < 3; d++) {
        ta.src[2 + d] = dW0 + (size_t)d * 480 * 1024;
        ta.dst[2 + d] = W480 + (size_t)(512 + d * 1024) * 480;
        ta.K[2 + d] = 480; ta.N[2 + d] = 1024;
        ta.src[5 + d] = dW1 + (size_t)d * 1024 * 512;
        ta.dst[5 + d] = dW1t + (size_t)d * 512 * 1024;
        ta.K[5 + d] = 1024; ta.N[5 + d] = 512;
    }
    ta.src[8] = u0; ta.dst[8] = u0t; ta.K[8] = 512; ta.N[8] = 32;
    int acc_t = 0;
    for (int i = 0; i < 9; i++) { ta.base[i] = acc_t; acc_t += (ta.K[i] >> 5) * (ta.N[i] >> 5); }

    prep_kernel<<<PREP_CV, 256, 0, stream>>>(ta, ws, 18560, x, tables, embBF, v1, v1bf);

    // ---- fused K=480 layer: [B,480] @ [480, 512+3*1024] -> Z480bf (bf16) ----
    GemmGroups g480;
    g480.A[0] = embBF; g480.Bt[0] = W480; g480.C[0] = Z480bf;
    g480.stats[0] = stats480; g480.N[0] = 3584; g480.K[0] = 480; g480.base[0] = 0; g480.obf[0] = 1;
    for (int i = 1; i < 4; i++) { g480.base[i] = 0x7fffffff; g480.A[i] = nullptr; g480.Bt[i] = nullptr; g480.C[i] = nullptr; g480.stats[i] = nullptr; g480.N[i] = 0; g480.K[i] = 32; g480.obf[i] = 0; }
    gemm_grouped<<<896, 256, 0, stream>>>(g480);
    bn480_kernel<<<7168, 256, 0, stream>>>(Z480bf, stats480, hg0, hbt0, dg0, dbt0, Z0BF, ZD0BF);

    // ---- grouped layer-1: hyper1 (N=1024,K=512) + 3x dW1 (N=512,K=1024), f32 out ----
    GemmGroups g2;
    g2.A[0] = Z0BF; g2.Bt[0] = hW1t; g2.C[0] = Z1scr;
    g2.stats[0] = statsH; g2.N[0] = 1024; g2.K[0] = 512; g2.base[0] = 0; g2.obf[0] = 0;
    for (int d = 0; d < 3; d++) {
        g2.A[1 + d] = ZD0BF + (size_t)d * 4194304;
        g2.Bt[1 + d] = dW1t + (size_t)d * 524288;
        g2.C[1 + d] = SCR1 + (size_t)d * 2097152;
        g2.stats[1 + d] = statsD1 + d * 1024;
        g2.N[1 + d] = 512; g2.K[1 + d] = 1024;
        g2.base[1 + d] = 256 + d * 128;
        g2.obf[1 + d] = 0;
    }
    gemm_grouped<<<640, 256, 0, stream>>>(g2);
    bn_l1_kernel<<<5120, 256, 0, stream>>>(Z1scr, SCR1, statsH, statsD1, hg1, hbt1, dg1, dbt1, Hbf, D1BF);

    gemm_bf16_N32<<<dim3(32, 3), 256, 0, stream>>>(D1BF, u0t, Afac);
    adapter_core<<<1024, 256, 0, stream>>>(Afac, Hbf, v0, u1, bl0, C2);
    gram_kernel<<<dim3(16, 3), 256, 0, stream>>>(C2, gramM, gramS);
    stats_t2_kernel<<<3, 256, 0, stream>>>(gramM, gramS, v1bf, statsT2);
    head_kernel<<<1024, 256, 0, stream>>>(x, C2, D1BF, statsT2, g1, b1, dWo, dbo, v1bf, out);
    (void)in_sizes; (void)n_in; (void)out_size; (void)ws_size;
}

// Round 9
// 272.109 us; speedup vs baseline: 3.5278x; 1.0432x over previous
//
#include <hip/hip_runtime.h>
#include <hip/hip_bf16.h>
#include <math.h>

// Problem constants (fixed by the reference)
#define F_   30
#define E_   16
#define B_   4096
#define IN_  480      // F*E
#define H1_  1024
#define H2_  512
#define K_   32
#define HH_  512
#define D_   3
#define V_   10000
#define EPS_ 1e-5f

typedef __attribute__((ext_vector_type(8))) short bf16x8;   // MFMA A/B frag (8 bf16)
typedef __attribute__((ext_vector_type(4))) float f32x4;    // MFMA C/D frag
typedef __attribute__((ext_vector_type(8))) unsigned short u16x8;

__device__ __forceinline__ unsigned short f2bf(float f) {   // RNE f32->bf16
    unsigned u = __builtin_bit_cast(unsigned, f);
    u += 0x7FFFu + ((u >> 16) & 1u);
    return (unsigned short)(u >> 16);
}
__device__ __forceinline__ float bf2f(unsigned short h) {
    return __builtin_bit_cast(float, ((unsigned)h) << 16);
}
__device__ __forceinline__ void gload_lds16(const unsigned short* g, unsigned short* l) {
    typedef unsigned int __attribute__((address_space(1))) guint;
    typedef unsigned int __attribute__((address_space(3))) luint;
    __builtin_amdgcn_global_load_lds((const guint*)g, (luint*)l, 16, 0, 0);
}

// ---------------------------------------------------------------------------
// Merged prep: zero stats | gather emb->bf16 | weight transpose->bf16 | v1->bf16
struct TransArgs {
    const float* src[9];
    unsigned short* dst[9];
    int K[9], N[9], base[9];
};
#define PREP_ZB   73
#define PREP_GA   (PREP_ZB + 960)        // 1033
#define PREP_TR   (PREP_GA + 3744)       // 4777
#define PREP_CV   (PREP_TR + 64)         // 4841
__global__ __launch_bounds__(256) void prep_kernel(TransArgs ta,
                                                   float* __restrict__ zero_p, int zero_n,
                                                   const int* __restrict__ x,
                                                   const float* __restrict__ tables,
                                                   unsigned short* __restrict__ emb,
                                                   const float* __restrict__ v1,
                                                   unsigned short* __restrict__ v1bf) {
    __shared__ float tile[32][33];
    int blk = blockIdx.x;
    int t = threadIdx.x;
    if (blk < PREP_ZB) {
        int i = blk * 256 + t;
        if (i < zero_n) zero_p[i] = 0.f;
    } else if (blk < PREP_GA) {
        int idx = (blk - PREP_ZB) * 256 + t;       // B_*F_*2 total
        int b = idx / (F_ * 2);
        int r = idx - b * (F_ * 2);
        int f = r >> 1, h = r & 1;
        int row = x[f * B_ + b];
        const float4* src = reinterpret_cast<const float4*>(tables + ((size_t)f * V_ + row) * E_ + h * 8);
        float4 v0 = src[0], v1v = src[1];
        u16x8 o;
        o[0]=f2bf(v0.x); o[1]=f2bf(v0.y); o[2]=f2bf(v0.z); o[3]=f2bf(v0.w);
        o[4]=f2bf(v1v.x); o[5]=f2bf(v1v.y); o[6]=f2bf(v1v.z); o[7]=f2bf(v1v.w);
        *reinterpret_cast<u16x8*>(emb + (size_t)b * IN_ + f * E_ + h * 8) = o;
    } else if (blk < PREP_TR) {
        int gblk = blk - PREP_GA;
        int seg = 0;
#pragma unroll
        for (int i = 1; i < 9; i++) if (gblk >= ta.base[i]) seg = i;
        int tix = gblk - ta.base[seg];
        int Kd = ta.K[seg], Nd = ta.N[seg];
        int tn = Nd >> 5;
        int k0 = (tix / tn) << 5;
        int n0 = (tix - (tix / tn) * tn) << 5;
        const float* src = ta.src[seg];
        unsigned short* dst = ta.dst[seg];
        int c = t & 31, rr = t >> 5;
#pragma unroll
        for (int i = 0; i < 4; i++) {
            int r = rr + i * 8;
            tile[r][c] = src[(size_t)(k0 + r) * Nd + n0 + c];
        }
        __syncthreads();
#pragma unroll
        for (int i = 0; i < 4; i++) {
            int r = rr + i * 8;   // n index
            dst[(size_t)(n0 + r) * Kd + k0 + c] = f2bf(tile[c][r]);
        }
    } else {
        int i = (blk - PREP_TR) * 256 + t;
        if (i < K_ * H2_) v1bf[i] = f2bf(v1[i]);
    }
}

// ---------------------------------------------------------------------------
// Grouped bf16 GEMM (used for the K=480 layer): C = A @ Bt^T, 128x128 tile,
// BK=32, 4 waves, mfma 16x16x32. Epilogue: bf16/f32 C + per-column sum/sumsq.
struct GemmGroups {
    const unsigned short* A[4];
    const unsigned short* Bt[4];
    void* C[4];
    float* stats[4];
    int N[4], K[4], base[4], obf[4];
};
__global__ __launch_bounds__(256) void gemm_grouped(GemmGroups p) {
    __shared__ unsigned short sA[128 * 32];
    __shared__ unsigned short sB[128 * 32];
    int blk = blockIdx.x;
    int g = 0;
#pragma unroll
    for (int i = 1; i < 4; i++) if (blk >= p.base[i]) g = i;
    int tix = blk - p.base[g];
    int N = p.N[g], K = p.K[g];
    const unsigned short* A = p.A[g];
    const unsigned short* Bt = p.Bt[g];
    float* stats = p.stats[g];
    int bm = (tix & 31) << 7;
    int bn = (tix >> 5) << 7;

    int tid = threadIdx.x;
    int l = tid & 63, w = tid >> 6;
    int wr = w >> 1, wc = w & 1;
    const unsigned short* Ab = A + (size_t)bm * K;
    const unsigned short* Bb = Bt + (size_t)bn * K;
    f32x4 acc[4][4] = {};
    int n0c = tid, n1c = tid + 256;
    int r0 = n0c >> 2, lc0 = (n0c & 3) ^ ((r0 >> 1) & 3);
    int r1 = n1c >> 2, lc1 = (n1c & 3) ^ ((r1 >> 1) & 3);
    int kg = l >> 4, lr = l & 15;
    for (int k0 = 0; k0 < K; k0 += 32) {
        gload_lds16(Ab + (size_t)r0 * K + k0 + lc0 * 8, &sA[n0c * 8]);
        gload_lds16(Ab + (size_t)r1 * K + k0 + lc1 * 8, &sA[n1c * 8]);
        gload_lds16(Bb + (size_t)r0 * K + k0 + lc0 * 8, &sB[n0c * 8]);
        gload_lds16(Bb + (size_t)r1 * K + k0 + lc1 * 8, &sB[n1c * 8]);
        __syncthreads();
        bf16x8 af[4], bfr[4];
#pragma unroll
        for (int m = 0; m < 4; m++) {
            int R = (wr << 6) + (m << 4) + lr;
            af[m] = *reinterpret_cast<const bf16x8*>(&sA[R * 32 + ((kg ^ ((R >> 1) & 3)) << 3)]);
        }
#pragma unroll
        for (int n = 0; n < 4; n++) {
            int R = (wc << 6) + (n << 4) + lr;
            bfr[n] = *reinterpret_cast<const bf16x8*>(&sB[R * 32 + ((kg ^ ((R >> 1) & 3)) << 3)]);
        }
#pragma unroll
        for (int m = 0; m < 4; m++)
#pragma unroll
            for (int n = 0; n < 4; n++)
                acc[m][n] = __builtin_amdgcn_mfma_f32_16x16x32_bf16(af[m], bfr[n], acc[m][n], 0, 0, 0);
        __syncthreads();
    }
    int orow = bm + (wr << 6) + (kg << 2);
    int ocol = bn + (wc << 6) + lr;
    if (p.obf[g]) {
        unsigned short* Cb = (unsigned short*)p.C[g];
#pragma unroll
        for (int m = 0; m < 4; m++)
#pragma unroll
            for (int n = 0; n < 4; n++)
#pragma unroll
                for (int j = 0; j < 4; j++)
                    Cb[(size_t)(orow + (m << 4) + j) * N + ocol + (n << 4)] = f2bf(acc[m][n][j]);
    } else {
        float* C = (float*)p.C[g];
#pragma unroll
        for (int m = 0; m < 4; m++)
#pragma unroll
            for (int n = 0; n < 4; n++)
#pragma unroll
                for (int j = 0; j < 4; j++)
                    C[(size_t)(orow + (m << 4) + j) * N + ocol + (n << 4)] = acc[m][n][j];
    }
#pragma unroll
    for (int n = 0; n < 4; n++) {
        float s = 0.f, ss = 0.f;
#pragma unroll
        for (int m = 0; m < 4; m++)
#pragma unroll
            for (int j = 0; j < 4; j++) {
                float v = acc[m][n][j];
                s += v; ss += v * v;
            }
        s  += __shfl_xor(s, 16);  s  += __shfl_xor(s, 32);
        ss += __shfl_xor(ss, 16); ss += __shfl_xor(ss, 32);
        if (l < 16) {
            int col = bn + (wc << 6) + (n << 4) + lr;
            atomicAdd(&stats[col], s);
            atomicAdd(&stats[N + col], ss);
        }
    }
}

// ---------------------------------------------------------------------------
// Layer-1 grouped GEMM with BN+ReLU fused into the A-operand path.
// A = relu(g0*(Z480-mean)*rsqrt(var+eps)+bt0) computed on the fly from raw
// pre-BN Z480bf (cols [colbase, colbase+K)) using a per-block LDS affine table
// built from stats480. A is reg-staged (load->affine->ds_write swizzled);
// B uses global_load_lds. C written bf16 + column stats from f32 accumulators.
struct L1Groups {
    const unsigned short* Bt[4];
    unsigned short* C[4];
    float* stats[4];
    const float* gg[4];      // layer-0 BN gamma for these columns
    const float* gb[4];      // layer-0 BN beta
    int N[4], K[4], base[4], colbase[4];
};
__global__ __launch_bounds__(256) void gemm_l1(L1Groups p,
                                               const unsigned short* __restrict__ Z480bf,
                                               const float* __restrict__ stats480) {
    __shared__ unsigned short sA[128 * 32];
    __shared__ unsigned short sB[128 * 32];
    __shared__ float2 aff[1024];
    int blk = blockIdx.x;
    int g = 0;
#pragma unroll
    for (int i = 1; i < 4; i++) if (blk >= p.base[i]) g = i;
    int tix = blk - p.base[g];
    int N = p.N[g], K = p.K[g], colbase = p.colbase[g];
    const unsigned short* Bt = p.Bt[g];
    float* stats = p.stats[g];
    const float* gg = p.gg[g];
    const float* gb = p.gb[g];
    int tid = threadIdx.x;
    for (int k = tid; k < K; k += 256) {
        int col = colbase + k;
        float S = stats480[col], SS = stats480[3584 + col];
        float m = S * (1.f / B_);
        float var = (SS - S * m) * (1.f / B_);
        float rs = rsqrtf(var + EPS_);
        float s = gg[k] * rs;
        aff[k] = make_float2(s, gb[k] - m * s);
    }
    int bm = (tix & 31) << 7;
    int bn = (tix >> 5) << 7;
    const unsigned short* Bb = Bt + (size_t)bn * K;
    int l = tid & 63, w = tid >> 6;
    int wr = w >> 1, wc = w & 1;
    f32x4 acc[4][4] = {};
    int n0c = tid, n1c = tid + 256;
    int r0 = n0c >> 2, lc0 = (n0c & 3) ^ ((r0 >> 1) & 3);
    int r1 = n1c >> 2, lc1 = (n1c & 3) ^ ((r1 >> 1) & 3);
    int kg = l >> 4, lr = l & 15;
    const unsigned short* Arow0 = Z480bf + (size_t)(bm + r0) * 3584 + colbase + lc0 * 8;
    const unsigned short* Arow1 = Z480bf + (size_t)(bm + r1) * 3584 + colbase + lc1 * 8;
    __syncthreads();                       // aff table ready
    for (int k0 = 0; k0 < K; k0 += 32) {
        gload_lds16(Bb + (size_t)r0 * K + k0 + lc0 * 8, &sB[n0c * 8]);
        gload_lds16(Bb + (size_t)r1 * K + k0 + lc1 * 8, &sB[n1c * 8]);
        u16x8 za = *reinterpret_cast<const u16x8*>(Arow0 + k0);
        u16x8 zb = *reinterpret_cast<const u16x8*>(Arow1 + k0);
        u16x8 oa, ob;
#pragma unroll
        for (int q = 0; q < 8; q++) {
            float2 pa = aff[k0 + lc0 * 8 + q];
            oa[q] = f2bf(fmaxf(0.f, bf2f(za[q]) * pa.x + pa.y));
            float2 pb = aff[k0 + lc1 * 8 + q];
            ob[q] = f2bf(fmaxf(0.f, bf2f(zb[q]) * pb.x + pb.y));
        }
        *reinterpret_cast<u16x8*>(&sA[n0c * 8]) = oa;
        *reinterpret_cast<u16x8*>(&sA[n1c * 8]) = ob;
        __syncthreads();
        bf16x8 af[4], bfr[4];
#pragma unroll
        for (int m = 0; m < 4; m++) {
            int R = (wr << 6) + (m << 4) + lr;
            af[m] = *reinterpret_cast<const bf16x8*>(&sA[R * 32 + ((kg ^ ((R >> 1) & 3)) << 3)]);
        }
#pragma unroll
        for (int n = 0; n < 4; n++) {
            int R = (wc << 6) + (n << 4) + lr;
            bfr[n] = *reinterpret_cast<const bf16x8*>(&sB[R * 32 + ((kg ^ ((R >> 1) & 3)) << 3)]);
        }
#pragma unroll
        for (int m = 0; m < 4; m++)
#pragma unroll
            for (int n = 0; n < 4; n++)
                acc[m][n] = __builtin_amdgcn_mfma_f32_16x16x32_bf16(af[m], bfr[n], acc[m][n], 0, 0, 0);
        __syncthreads();
    }
    int orow = bm + (wr << 6) + (kg << 2);
    int ocol = bn + (wc << 6) + lr;
    unsigned short* Cb = p.C[g];
#pragma unroll
    for (int m = 0; m < 4; m++)
#pragma unroll
        for (int n = 0; n < 4; n++)
#pragma unroll
            for (int j = 0; j < 4; j++)
                Cb[(size_t)(orow + (m << 4) + j) * N + ocol + (n << 4)] = f2bf(acc[m][n][j]);
#pragma unroll
    for (int n = 0; n < 4; n++) {
        float s = 0.f, ss = 0.f;
#pragma unroll
        for (int m = 0; m < 4; m++)
#pragma unroll
            for (int j = 0; j < 4; j++) {
                float v = acc[m][n][j];
                s += v; ss += v * v;
            }
        s  += __shfl_xor(s, 16);  s  += __shfl_xor(s, 32);
        ss += __shfl_xor(ss, 16); ss += __shfl_xor(ss, 32);
        if (l < 16) {
            int col = bn + (wc << 6) + (n << 4) + lr;
            atomicAdd(&stats[col], s);
            atomicAdd(&stats[N + col], ss);
        }
    }
}

// ---------------------------------------------------------------------------
// Afac[d][M,32] = D1[d][M,K] @ u0t[32,K]^T (bf16). z-batched over domains.
__global__ __launch_bounds__(256) void gemm_bf16_N32(const unsigned short* __restrict__ D1BF,
                                                     const unsigned short* __restrict__ Bt,
                                                     float* __restrict__ Afac) {
    __shared__ unsigned short sA[128 * 32];
    __shared__ unsigned short sB[32 * 32];
    int d = blockIdx.y;
    const unsigned short* A = D1BF + (size_t)d * B_ * H2_;
    float* C = Afac + (size_t)d * B_ * 32;
    const int K = 512;
    int tid = threadIdx.x;
    int l = tid & 63, w = tid >> 6;
    int bm = blockIdx.x << 7;
    const unsigned short* Ab = A + (size_t)bm * K;
    f32x4 acc[2][2] = {};
    int n0c = tid, n1c = tid + 256;
    int r0 = n0c >> 2, lc0 = (n0c & 3) ^ ((r0 >> 1) & 3);
    int r1 = n1c >> 2, lc1 = (n1c & 3) ^ ((r1 >> 1) & 3);
    int kg = l >> 4, lr = l & 15;
    for (int k0 = 0; k0 < K; k0 += 32) {
        gload_lds16(Ab + (size_t)r0 * K + k0 + lc0 * 8, &sA[n0c * 8]);
        gload_lds16(Ab + (size_t)r1 * K + k0 + lc1 * 8, &sA[n1c * 8]);
        if (tid < 128)
            gload_lds16(Bt + (size_t)r0 * K + k0 + lc0 * 8, &sB[n0c * 8]);
        __syncthreads();
        bf16x8 af[2], bfr[2];
#pragma unroll
        for (int m = 0; m < 2; m++) {
            int R = (w << 5) + (m << 4) + lr;
            af[m] = *reinterpret_cast<const bf16x8*>(&sA[R * 32 + ((kg ^ ((R >> 1) & 3)) << 3)]);
        }
#pragma unroll
        for (int n = 0; n < 2; n++) {
            int R = (n << 4) + lr;
            bfr[n] = *reinterpret_cast<const bf16x8*>(&sB[R * 32 + ((kg ^ ((R >> 1) & 3)) << 3)]);
        }
#pragma unroll
        for (int m = 0; m < 2; m++)
#pragma unroll
            for (int n = 0; n < 2; n++)
                acc[m][n] = __builtin_amdgcn_mfma_f32_16x16x32_bf16(af[m], bfr[n], acc[m][n], 0, 0, 0);
        __syncthreads();
    }
    int orow = bm + (w << 5) + (kg << 2);
#pragma unroll
    for (int m = 0; m < 2; m++)
#pragma unroll
        for (int n = 0; n < 2; n++)
#pragma unroll
            for (int j = 0; j < 4; j++)
                C[(size_t)(orow + (m << 4) + j) * 32 + (n << 4) + lr] = acc[m][n][j];
}

// ---------------------------------------------------------------------------
// Merged BN+ReLU for layer-1 outputs (bf16 in, bf16 out):
//  blocks [0,2048):   hyper H: Z1BF [4096][1024] -> Hbf
//  blocks [2048,5120): domains: SD1BF [3*4096][512] -> D1BF
__global__ __launch_bounds__(256) void bn_l1_kernel(const unsigned short* __restrict__ Z1BF,
                                                    const unsigned short* __restrict__ SD1BF,
                                                    const float* __restrict__ statsH,
                                                    const float* __restrict__ statsD1,
                                                    const float* __restrict__ hg1,
                                                    const float* __restrict__ hbt1,
                                                    const float* __restrict__ dg1,
                                                    const float* __restrict__ dbt1,
                                                    unsigned short* __restrict__ Hbf,
                                                    unsigned short* __restrict__ D1BF) {
    int gidx = blockIdx.x * 256 + threadIdx.x;
    const unsigned short* Z; const float* stats; const float* g; const float* bt;
    unsigned short* outp; int c0; int idx;
    if (gidx < 524288) {               // H: 4096*128
        idx = gidx;
        c0 = (idx & 127) * 8;
        Z = Z1BF; stats = statsH; g = hg1; bt = hbt1; outp = Hbf;
    } else {                           // D1: 12288*64
        idx = gidx - 524288;
        int row = idx >> 6;
        int d = row >> 12;
        c0 = (idx & 63) * 8;
        Z = SD1BF; stats = statsD1 + d * 1024; g = dg1 + d * 512; bt = dbt1 + d * 512; outp = D1BF;
    }
    int sh = (gidx < 524288) ? 1024 : 512;
    u16x8 v = *reinterpret_cast<const u16x8*>(Z + (size_t)idx * 8);
    u16x8 o;
#pragma unroll
    for (int q = 0; q < 8; q++) {
        float S = stats[c0 + q], SS = stats[sh + c0 + q];
        float m = S * (1.f / B_);
        float var = (SS - S * m) * (1.f / B_);
        float rs = rsqrtf(var + EPS_);
        o[q] = f2bf(fmaxf(0.f, g[c0 + q] * (bf2f(v[q]) - m) * rs + bt[c0 + q]));
    }
    *reinterpret_cast<u16x8*>(outp + (size_t)idx * 8) = o;
}

// ---------------------------------------------------------------------------
// Adapter core: one wave per batch row, all 3 domains. hreg = H column (32 VGPR).
__global__ __launch_bounds__(256) void adapter_core(const float* __restrict__ Afac,
                                                    const unsigned short* __restrict__ Hbf,
                                                    const float* __restrict__ v0,
                                                    const float* __restrict__ u1,
                                                    const float* __restrict__ bl0,
                                                    float* __restrict__ C2) {
    __shared__ float sv0[K_ * K_];
    __shared__ float su1[K_ * K_];
    int t = threadIdx.x;
    reinterpret_cast<float4*>(sv0)[t] = reinterpret_cast<const float4*>(v0)[t];
    reinterpret_cast<float4*>(su1)[t] = reinterpret_cast<const float4*>(u1)[t];
    __syncthreads();
    int w = t >> 6, l = t & 63;
    int i = l & 31;
    int b = blockIdx.x * 4 + w;
    float hreg[32];
#pragma unroll
    for (int k = 0; k < 32; k++) hreg[k] = bf2f(Hbf[(size_t)b * 1024 + k * 32 + i]);
    float bl0i = bl0[i];
#pragma unroll
    for (int d = 0; d < 3; d++) {
        float a = Afac[(size_t)d * 131072 + b * 32 + i];
        float c = 0.f;
#pragma unroll
        for (int k = 0; k < 32; k++) c += __shfl(a, k) * hreg[k];
        float targ = bl0i;
#pragma unroll
        for (int k = 0; k < 32; k++) targ += __shfl(c, k) * sv0[k * 32 + i];
        float tv = 1.f / (1.f + expf(-targ));
        float a2 = 0.f;
#pragma unroll
        for (int k = 0; k < 32; k++) a2 += __shfl(tv, k) * su1[k * 32 + i];
        float c2 = 0.f;
#pragma unroll
        for (int k = 0; k < 32; k++) c2 += __shfl(a2, k) * hreg[k];
        if (l < 32) C2[(size_t)d * 131072 + b * 32 + i] = c2;
    }
}

// ---------------------------------------------------------------------------
// Gram: per domain, M = C2^T C2 (32x32) and s = colsum(C2), atomics over 16 row-blocks.
__global__ __launch_bounds__(256) void gram_kernel(const float* __restrict__ C2,
                                                   float* __restrict__ gramM,
                                                   float* __restrict__ gramS) {
    __shared__ float sc[256 * 32];     // 32KB
    int z = blockIdx.y;
    const float* Cz = C2 + (size_t)z * 131072 + (size_t)blockIdx.x * 256 * 32;
    int t = threadIdx.x;
#pragma unroll
    for (int i = 0; i < 8; i++)
        reinterpret_cast<float4*>(sc)[t + i * 256] = reinterpret_cast<const float4*>(Cz)[t + i * 256];
    __syncthreads();
    int k = t >> 3, k4 = (t & 7) << 2;
    float m0 = 0.f, m1 = 0.f, m2 = 0.f, m3 = 0.f;
    for (int r = 0; r < 256; r++) {
        float ck = sc[r * 32 + k];
        m0 += ck * sc[r * 32 + k4 + 0];
        m1 += ck * sc[r * 32 + k4 + 1];
        m2 += ck * sc[r * 32 + k4 + 2];
        m3 += ck * sc[r * 32 + k4 + 3];
    }
    float* Mz = gramM + z * 1024 + k * 32 + k4;
    atomicAdd(&Mz[0], m0); atomicAdd(&Mz[1], m1);
    atomicAdd(&Mz[2], m2); atomicAdd(&Mz[3], m3);
    if (t < 32) {
        float s = 0.f;
        for (int r = 0; r < 256; r++) s += sc[r * 32 + t];
        atomicAdd(&gramS[z * 32 + t], s);
    }
}

// ---------------------------------------------------------------------------
// statsT2[z][j] = s_z . v1[:,j]; statsT2[z][512+j] = v1[:,j]^T M_z v1[:,j]
__global__ __launch_bounds__(256) void stats_t2_kernel(const float* __restrict__ gramM,
                                                       const float* __restrict__ gramS,
                                                       const unsigned short* __restrict__ v1bf,
                                                       float* __restrict__ statsT2) {
    __shared__ float sM[1024];
    __shared__ float sS[32];
    __shared__ unsigned short sv1[K_ * H2_];   // 32KB
    int z = blockIdx.x;
    int t = threadIdx.x;
    reinterpret_cast<float4*>(sM)[t] = reinterpret_cast<const float4*>(gramM + z * 1024)[t];
    if (t < 8) reinterpret_cast<float4*>(sS)[t] = reinterpret_cast<const float4*>(gramS + z * 32)[t];
#pragma unroll
    for (int i = 0; i < 8; i++)
        reinterpret_cast<u16x8*>(sv1)[t + i * 256] = reinterpret_cast<const u16x8*>(v1bf)[t + i * 256];
    __syncthreads();
#pragma unroll
    for (int jj = 0; jj < 2; jj++) {
        int j = t + jj * 256;
        float vj[32];
#pragma unroll
        for (int k = 0; k < 32; k++) vj[k] = bf2f(sv1[k * 512 + j]);
        float cs = 0.f, ssq = 0.f;
#pragma unroll
        for (int k = 0; k < 32; k++) {
            float wk = 0.f;
#pragma unroll
            for (int kp = 0; kp < 32; kp++) wk += sM[k * 32 + kp] * vj[kp];
            ssq += vj[k] * wk;
            cs += sS[k] * vj[k];
        }
        statsT2[z * 1024 + j] = cs;
        statsT2[z * 1024 + 512 + j] = ssq;
    }
}

// ---------------------------------------------------------------------------
// Head: per row b, d = x[-1][b]; T2 row computed on the fly from C2 row + v1;
// BN(unbiased) + D1 residual -> dot wo -> sigmoid. One wave per row, 4 rows/block.
__global__ __launch_bounds__(256) void head_kernel(const int* __restrict__ x,
                                                   const float* __restrict__ C2,
                                                   const unsigned short* __restrict__ D1BF,
                                                   const float* __restrict__ statsT2,
                                                   const float* __restrict__ g1,
                                                   const float* __restrict__ b1,
                                                   const float* __restrict__ dWo,
                                                   const float* __restrict__ dbo,
                                                   const unsigned short* __restrict__ v1bf,
                                                   float* __restrict__ out) {
    __shared__ unsigned short sv1[K_ * H2_];   // 32KB
    int t = threadIdx.x;
#pragma unroll
    for (int i = 0; i < 8; i++)
        reinterpret_cast<u16x8*>(sv1)[t + i * 256] = reinterpret_cast<const u16x8*>(v1bf)[t + i * 256];
    __syncthreads();
    int w = t >> 6, l = t & 63;
    int b = blockIdx.x * 4 + w;
    int d = x[(F_ - 1) * B_ + b];
    float cv = C2[((size_t)d * B_ + b) * 32 + (l & 31)];
    float o[8] = {};
#pragma unroll
    for (int k = 0; k < 32; k++) {
        float cb = __shfl(cv, k);
        u16x8 vv = *reinterpret_cast<const u16x8*>(&sv1[k * 512 + l * 8]);
#pragma unroll
        for (int q = 0; q < 8; q++) o[q] += cb * bf2f(vv[q]);
    }
    int j0 = l * 8;
    const float* cs = statsT2 + d * 1024;
    float4 Sa = *reinterpret_cast<const float4*>(cs + j0);
    float4 Sb = *reinterpret_cast<const float4*>(cs + j0 + 4);
    float4 Qa = *reinterpret_cast<const float4*>(cs + 512 + j0);
    float4 Qb = *reinterpret_cast<const float4*>(cs + 512 + j0 + 4);
    float4 Ga = *reinterpret_cast<const float4*>(g1 + j0);
    float4 Gb = *reinterpret_cast<const float4*>(g1 + j0 + 4);
    float4 Ba = *reinterpret_cast<const float4*>(b1 + j0);
    float4 Bb = *reinterpret_cast<const float4*>(b1 + j0 + 4);
    float4 Wa = *reinterpret_cast<const float4*>(dWo + d * 512 + j0);
    float4 Wb = *reinterpret_cast<const float4*>(dWo + d * 512 + j0 + 4);
    u16x8 d1v = *reinterpret_cast<const u16x8*>(D1BF + (size_t)d * 2097152 + (size_t)b * 512 + j0);
    float Sv[8] = {Sa.x,Sa.y,Sa.z,Sa.w,Sb.x,Sb.y,Sb.z,Sb.w};
    float Qv[8] = {Qa.x,Qa.y,Qa.z,Qa.w,Qb.x,Qb.y,Qb.z,Qb.w};
    float Gv[8] = {Ga.x,Ga.y,Ga.z,Ga.w,Gb.x,Gb.y,Gb.z,Gb.w};
    float Bv[8] = {Ba.x,Ba.y,Ba.z,Ba.w,Bb.x,Bb.y,Bb.z,Bb.w};
    float Wv[8] = {Wa.x,Wa.y,Wa.z,Wa.w,Wb.x,Wb.y,Wb.z,Wb.w};
    float p = 0.f;
#pragma unroll
    for (int q = 0; q < 8; q++) {
        float S = Sv[q], SS = Qv[q];
        float m = S * (1.f / B_);
        float var = (SS - S * m) * (1.f / (B_ - 1));
        float rs = rsqrtf(var + EPS_);
        float di = Gv[q] * (o[q] - m) * rs + Bv[q] + bf2f(d1v[q]);
        p += di * Wv[q];
    }
    p += __shfl_down(p, 32); p += __shfl_down(p, 16); p += __shfl_down(p, 8);
    p += __shfl_down(p, 4);  p += __shfl_down(p, 2);  p += __shfl_down(p, 1);
    if (l == 0) out[b] = 1.f / (1.f + expf(-(p + dbo[d])));
}

// ---------------------------------------------------------------------------
extern "C" void kernel_launch(void* const* d_in, const int* in_sizes, int n_in,
                              void* d_out, int out_size, void* d_ws, size_t ws_size,
                              hipStream_t stream) {
    const int*   x      = (const int*)  d_in[0];
    const float* tables = (const float*)d_in[1];
    const float* dW0  = (const float*)d_in[2];
    const float* dg0  = (const float*)d_in[4];
    const float* dbt0 = (const float*)d_in[5];
    const float* dW1  = (const float*)d_in[6];
    const float* dg1  = (const float*)d_in[8];
    const float* dbt1 = (const float*)d_in[9];
    const float* dWo  = (const float*)d_in[10];
    const float* dbo  = (const float*)d_in[11];
    const float* hW0  = (const float*)d_in[12];
    const float* hg0  = (const float*)d_in[14];
    const float* hbt0 = (const float*)d_in[15];
    const float* hW1  = (const float*)d_in[16];
    const float* hg1  = (const float*)d_in[18];
    const float* hbt1 = (const float*)d_in[19];
    const float* u0   = (const float*)d_in[20];
    const float* u1   = (const float*)d_in[21];
    const float* v0   = (const float*)d_in[22];
    const float* v1   = (const float*)d_in[23];
    const float* bl0  = (const float*)d_in[24];
    const float* g1   = (const float*)d_in[26];
    const float* b1   = (const float*)d_in[27];
    float* out = (float*)d_out;

    // ---- workspace layout (all 16B aligned) ----
    float* ws       = (float*)d_ws;
    float* stats480 = ws;                        // 7168
    float* statsH   = stats480 + 7168;           // 2048
    float* statsD1  = statsH + 2048;             // 3*1024 = 3072
    float* statsT2  = statsD1 + 3072;            // 3*1024 = 3072
    float* gramM    = statsT2 + 3072;            // 3*1024 = 3072
    float* gramS    = gramM + 3072;              // 128
    // zero region ends at 18560 floats
    float* Afac     = ws + 18560;                // 3*4096*32
    float* C2       = Afac + 393216;             // 3*4096*32
    unsigned short* Z480bf = (unsigned short*)(C2 + 393216);  // 4096*3584
    unsigned short* embBF = Z480bf + 14680064;   // 4096*480
    unsigned short* Z1BF  = embBF + 1966080;     // 4096*1024 (hyper1 pre-BN)
    unsigned short* SD1BF = Z1BF + 4194304;      // 3*4096*512 (domain1 pre-BN)
    unsigned short* Hbf   = SD1BF + 6291456;     // 4096*1024
    unsigned short* D1BF  = Hbf + 4194304;       // 3*4096*512
    unsigned short* W480  = D1BF + 6291456;      // [3584][480]
    unsigned short* hW1t  = W480 + 1720320;      // [1024][512]
    unsigned short* dW1t  = hW1t + 524288;       // [3][512][1024]
    unsigned short* u0t   = dW1t + 1572864;      // [32][512]
    unsigned short* v1bf  = u0t + 16384;         // [32][512]

    TransArgs ta;
    ta.src[0] = hW0; ta.dst[0] = W480; ta.K[0] = 480; ta.N[0] = 512;
    ta.src[1] = hW1; ta.dst[1] = hW1t; ta.K[1] = 512; ta.N[1] = 1024;
    for (int d = 0; d < 3; d++) {
        ta.src[2 + d] = dW0 + (size_t)d * 480 * 1024;
        ta.dst[2 + d] = W480 + (size_t)(512 + d * 1024) * 480;
        ta.K[2 + d] = 480; ta.N[2 + d] = 1024;
        ta.src[5 + d] = dW1 + (size_t)d * 1024 * 512;
        ta.dst[5 + d] = dW1t + (size_t)d * 512 * 1024;
        ta.K[5 + d] = 1024; ta.N[5 + d] = 512;
    }
    ta.src[8] = u0; ta.dst[8] = u0t; ta.K[8] = 512; ta.N[8] = 32;
    int acc_t = 0;
    for (int i = 0; i < 9; i++) { ta.base[i] = acc_t; acc_t += (ta.K[i] >> 5) * (ta.N[i] >> 5); }

    prep_kernel<<<PREP_CV, 256, 0, stream>>>(ta, ws, 18560, x, tables, embBF, v1, v1bf);

    // ---- fused K=480 layer: [B,480] @ [480, 512+3*1024] -> Z480bf (bf16 pre-BN) ----
    GemmGroups g480;
    g480.A[0] = embBF; g480.Bt[0] = W480; g480.C[0] = Z480bf;
    g480.stats[0] = stats480; g480.N[0] = 3584; g480.K[0] = 480; g480.base[0] = 0; g480.obf[0] = 1;
    for (int i = 1; i < 4; i++) { g480.base[i] = 0x7fffffff; g480.A[i] = nullptr; g480.Bt[i] = nullptr; g480.C[i] = nullptr; g480.stats[i] = nullptr; g480.N[i] = 0; g480.K[i] = 32; g480.obf[i] = 0; }
    gemm_grouped<<<896, 256, 0, stream>>>(g480);

    // ---- layer-1 grouped GEMM with fused BN+ReLU on A (longest-K groups first) ----
    L1Groups gl;
    for (int d = 0; d < 3; d++) {
        gl.Bt[d] = dW1t + (size_t)d * 524288;
        gl.C[d] = SD1BF + (size_t)d * 2097152;
        gl.stats[d] = statsD1 + d * 1024;
        gl.gg[d] = dg0 + d * 1024; gl.gb[d] = dbt0 + d * 1024;
        gl.N[d] = 512; gl.K[d] = 1024;
        gl.base[d] = d * 128;
        gl.colbase[d] = 512 + d * 1024;
    }
    gl.Bt[3] = hW1t; gl.C[3] = Z1BF; gl.stats[3] = statsH;
    gl.gg[3] = hg0; gl.gb[3] = hbt0;
    gl.N[3] = 1024; gl.K[3] = 512; gl.base[3] = 384; gl.colbase[3] = 0;
    gemm_l1<<<640, 256, 0, stream>>>(gl, Z480bf, stats480);

    bn_l1_kernel<<<5120, 256, 0, stream>>>(Z1BF, SD1BF, statsH, statsD1, hg1, hbt1, dg1, dbt1, Hbf, D1BF);

    gemm_bf16_N32<<<dim3(32, 3), 256, 0, stream>>>(D1BF, u0t, Afac);
    adapter_core<<<1024, 256, 0, stream>>>(Afac, Hbf, v0, u1, bl0, C2);
    gram_kernel<<<dim3(16, 3), 256, 0, stream>>>(C2, gramM, gramS);
    stats_t2_kernel<<<3, 256, 0, stream>>>(gramM, gramS, v1bf, statsT2);
    head_kernel<<<1024, 256, 0, stream>>>(x, C2, D1BF, statsT2, g1, b1, dWo, dbo, v1bf, out);
    (void)in_sizes; (void)n_in; (void)out_size; (void)ws_size;
}